// Round 6
// baseline (372.880 us; speedup 1.0000x reference)
//
#include <hip/hip_runtime.h>
#include <stdint.h>

// ---------------------------------------------------------------------------
// EncoderBlock: pre-norm transformer block, MI355X (gfx950).
// External dtype: FP32. Internal: bf16 MFMA, fp32 accum, fp32 residual.
// B=2 S=2048 D=1024 H=16 DK=64 DFF=4096 WINDOW=128 GLOBAL=16
// Round 13: gemm256 v5 — ONE window per K-tile (was 4 phases). Per window:
//   GBAR; stage A,B(t+1) [8x global_load_lds]; VM(8); GBAR;
//   { 8x B ds_read + 8x(2 A ds_read + 8 MFMA) — compiler-pipelined }
// 64 MFMA/wave per barrier pair (was 16): sync overhead amortized 4x.
// Staging shifted one window late (prologue pre-stages t0+t1) so VM(8)
// retires tile t while t+1 flies a full window (~2800cyc >= HBM latency).
// R3 validated this window shape; its regression was uncoalesced per-lane
// B loads (FETCH 2x) — here B stages via global_load_lds like A.
// Graph level (round-12, kept): Wo split-K4 + fused reduce4_ln.
// ---------------------------------------------------------------------------

typedef unsigned short u16;
typedef unsigned int   u32;
typedef __attribute__((ext_vector_type(8))) short  short8;  // 8 bf16 (4 VGPRs)
typedef __attribute__((ext_vector_type(4))) float  f32x4;

#define S_LEN   2048
#define D_MODEL 1024
#define ROWS    4096   // B*S

__device__ __forceinline__ float bf2f(u16 u) {
  union { u32 i; float f; } v; v.i = ((u32)u) << 16; return v.f;
}
__device__ __forceinline__ float bflo(u32 u) {
  union { u32 i; float f; } v; v.i = u << 16; return v.f;
}
__device__ __forceinline__ float bfhi(u32 u) {
  union { u32 i; float f; } v; v.i = u & 0xffff0000u; return v.f;
}
__device__ __forceinline__ u16 f2bf(float f) {
  union { float f; u32 i; } v; v.f = f;
  u32 r = v.i + 0x7fffu + ((v.i >> 16) & 1u);
  return (u16)(r >> 16);
}

// Direct global->LDS copy, 16B/lane (m97). Lands at wave base + lane*16.
__device__ __forceinline__ void gld_lds16(const u16* g, u16* l) {
  __attribute__((address_space(3))) u32* lp =
      reinterpret_cast<__attribute__((address_space(3))) u32*>(
          reinterpret_cast<uintptr_t>(l));
  const __attribute__((address_space(1))) u32* gp =
      reinterpret_cast<const __attribute__((address_space(1))) u32*>(
          reinterpret_cast<uintptr_t>(g));
  __builtin_amdgcn_global_load_lds(gp, lp, 16, 0, 0);
}

#define GBAR  asm volatile("s_barrier" ::: "memory")
#define VM(n) asm volatile("s_waitcnt vmcnt(" #n ")" ::: "memory")

// k-chunk rotate swizzle on the GLOBAL source (LDS linear): verified
// bank-conflict-free (SQ_LDS_BANK_CONFLICT = 0 across rounds 5-12).
#define STAGE_A(buf, t, hm) do {                                              \
    gld_lds16(pA##hm + (size_t)(t) * 64,      &Ald[buf][0][(hm)*4096 + ldst]);\
    gld_lds16(pA##hm + (size_t)(t) * 64 + 32, &Ald[buf][1][(hm)*4096 + ldst]);\
  } while (0)

#define STAGE_B(buf, t, hm) do {                                              \
    gld_lds16(pB##hm + (size_t)(t) * 64,      &Bld[buf][0][(hm)*4096 + ldst]);\
    gld_lds16(pB##hm + (size_t)(t) * 64 + 32, &Bld[buf][1][(hm)*4096 + ldst]);\
  } while (0)

// Whole K-tile compute: B frags once, then 8 mi-groups of {2 A reads,
// 8 MFMA}. No manual lgkm waits — compiler pipelines (m97-verified).
#define COMPUTE(rb) do {                                                      \
    short8 bfv[4][2];                                                         \
    _Pragma("unroll") for (int nj = 0; nj < 4; ++nj) {                        \
      bfv[nj][0] = *(const short8*)&Bld[rb][0][brow + nj * 512];              \
      bfv[nj][1] = *(const short8*)&Bld[rb][1][brow + nj * 512]; }            \
    __builtin_amdgcn_s_setprio(1);                                            \
    _Pragma("unroll") for (int mi = 0; mi < 8; ++mi) {                        \
      short8 a0 = *(const short8*)&Ald[rb][0][arow + mi * 512];               \
      short8 a1 = *(const short8*)&Ald[rb][1][arow + mi * 512];               \
      _Pragma("unroll") for (int nj = 0; nj < 4; ++nj)                        \
        acc[mi][nj] = __builtin_amdgcn_mfma_f32_16x16x32_bf16(                \
            a0, bfv[nj][0], acc[mi][nj], 0, 0, 0);                            \
      _Pragma("unroll") for (int nj = 0; nj < 4; ++nj)                        \
        acc[mi][nj] = __builtin_amdgcn_mfma_f32_16x16x32_bf16(                \
            a1, bfv[nj][1], acc[mi][nj], 0, 0, 0);                            \
    }                                                                         \
    __builtin_amdgcn_s_setprio(0);                                            \
  } while (0)

// window t (1 <= t <= NT-2): stage t+1 into buf[rb^1], compute tile t.
// BAR#1 closes all waves' reads of buf[rb^1] (prev window) before restage;
// VM(8) retires tile t's stage (issued one window ago), keeps t+1 flying;
// BAR#2 publishes all waves' stage(t) writes before this wave's reads.
#define GTILE_MID(t, rb) do {                                                 \
    GBAR;                                                                     \
    STAGE_A((rb)^1, (t) + 1, 0); STAGE_A((rb)^1, (t) + 1, 1);                 \
    STAGE_B((rb)^1, (t) + 1, 0); STAGE_B((rb)^1, (t) + 1, 1);                 \
    VM(8);                                                                    \
    GBAR;                                                                     \
    COMPUTE(rb);                                                              \
  } while (0)

// ---------------------------------------------------------------------------
// gemm256 v5: 256x256 tile, BK=64, 512 threads (8 waves, 2M x 4N).
// LDS: A/B each [buf 2][khalf 2][256 rows x 32 elems] = 128 KiB total.
// EPI: 0 = bias, 1 = bias+gelu, 2 = raw bf16 partial (split-K via grid.z).
// ---------------------------------------------------------------------------
template <int EPI, int KC, int LDK>
__global__ __launch_bounds__(512) void gemm256(
    const u16* __restrict__ A, const u16* __restrict__ Bt,
    const float* __restrict__ bias, u16* __restrict__ C0,
    u16* __restrict__ C1, u16* __restrict__ C2, u16* __restrict__ C3,
    int N)
{
  __shared__ __attribute__((aligned(16))) u16 Ald[2][2][256 * 32];
  __shared__ __attribute__((aligned(16))) u16 Bld[2][2][256 * 32];

  const int tid  = threadIdx.x;
  const int w    = tid >> 6;
  const int lane = tid & 63;
  const int wm   = w >> 2;       // 0..1  (M half)
  const int wn   = w & 3;        // 0..3  (N quarter)
  const int lm   = lane & 15;
  const int kq   = lane >> 4;
  const int bm   = blockIdx.y * 256;
  const int bn   = blockIdx.x * 256;
  const int kz   = blockIdx.z;

  const u16* Ak = A  + (size_t)kz * KC;
  const u16* Bk = Bt + (size_t)kz * KC;
  u16* C = (kz == 0) ? C0 : (kz == 1) ? C1 : (kz == 2) ? C2 : C3;

  // read-side swizzled chunk slot (row bases are multiples of 16).
  const int rslot = ((kq + (lm >> 1)) & 3) * 8;
  const int arow  = (wm * 128 + lm) * 32 + rslot;   // + mi*512
  const int brow  = (wn * 64  + lm) * 32 + rslot;   // + nj*512

  // stage-side: lane covers row (lane>>2), LDS chunk slot (lane&3).
  const int gcoff = (((lane & 3) - (lane >> 3)) & 3) * 8;
  const int srow  = w * 16 + (lane >> 2);           // row within 128-half
  const int ldst  = w * 512;                        // wave LDS base (u16)

  const u16* pA0 = Ak + (size_t)(bm + srow) * LDK + gcoff;
  const u16* pA1 = pA0 + (size_t)128 * LDK;
  const u16* pB0 = Bk + (size_t)(bn + srow) * LDK + gcoff;
  const u16* pB1 = pB0 + (size_t)128 * LDK;

  f32x4 acc[8][4];
#pragma unroll
  for (int i = 0; i < 8; ++i)
#pragma unroll
    for (int j = 0; j < 4; ++j) acc[i][j] = (f32x4){0.f, 0.f, 0.f, 0.f};

  constexpr int NT = KC >> 6;   // K-tiles of 64 (even, >= 4 in all uses)

  // prologue: stage t0 -> buf0 and t1 -> buf1 (16 loads in flight).
  STAGE_A(0, 0, 0); STAGE_A(0, 0, 1);
  STAGE_B(0, 0, 0); STAGE_B(0, 0, 1);
  STAGE_A(1, 1, 0); STAGE_A(1, 1, 1);
  STAGE_B(1, 1, 0); STAGE_B(1, 1, 1);

  // window 0: no stage; VM(8) retires t0 (keeps t1 flying).
  VM(8);
  GBAR;
  COMPUTE(0);

  // windows 1 .. NT-2 (stage t+1), pair-unrolled for constant buf indices.
#pragma unroll 1
  for (int tp = 0; tp < (NT - 2) / 2; ++tp) {
    GTILE_MID(1 + 2 * tp, 1);
    GTILE_MID(2 + 2 * tp, 0);
  }

  // window NT-1 (odd -> buf1): drain and compute.
  GBAR;
  VM(0);
  GBAR;
  COMPUTE(1);

  const int r0 = kq * 4;
#pragma unroll
  for (int mi = 0; mi < 8; ++mi) {
#pragma unroll
    for (int r = 0; r < 4; ++r) {
      const int grow = bm + wm * 128 + mi * 16 + r0 + r;
#pragma unroll
      for (int nj = 0; nj < 4; ++nj) {
        const int gcol = bn + wn * 64 + nj * 16 + lm;
        float v = acc[mi][nj][r];
        if (EPI < 2) v += bias[gcol];
        if (EPI == 1) v = 0.5f * v * (1.0f + erff(v * 0.70710678118654752f));
        C[(size_t)grow * N + gcol] = f2bf(v);
      }
    }
  }
}

// out[idx] = P0[idx] + P1[idx] + bias[col] + res[idx]   (N fixed = 1024)
__global__ __launch_bounds__(256) void reduce2(
    const u16* __restrict__ P0, const u16* __restrict__ P1,
    const float* __restrict__ bias, const float* res, float* out)
{
  const size_t base = ((size_t)blockIdx.x * 256 + threadIdx.x) * 8;
  const int col = (int)(base & 1023);
  uint4 p0 = *(const uint4*)(P0 + base);
  uint4 p1 = *(const uint4*)(P1 + base);
  float4 b0 = *(const float4*)(bias + col);
  float4 b1 = *(const float4*)(bias + col + 4);
  float4 r0 = *(const float4*)(res + base);
  float4 r1 = *(const float4*)(res + base + 4);
  float4 o0, o1;
  o0.x = bflo(p0.x) + bflo(p1.x) + b0.x + r0.x;
  o0.y = bfhi(p0.x) + bfhi(p1.x) + b0.y + r0.y;
  o0.z = bflo(p0.y) + bflo(p1.y) + b0.z + r0.z;
  o0.w = bfhi(p0.y) + bfhi(p1.y) + b0.w + r0.w;
  o1.x = bflo(p0.z) + bflo(p1.z) + b1.x + r1.x;
  o1.y = bfhi(p0.z) + bfhi(p1.z) + b1.y + r1.y;
  o1.z = bflo(p0.w) + bflo(p1.w) + b1.z + r1.z;
  o1.w = bfhi(p0.w) + bfhi(p1.w) + b1.w + r1.w;
  *(float4*)(out + base) = o0;
  *(float4*)(out + base + 4) = o1;
}

// ---------------------------------------------------------------------------
// Fused Wo-boundary: X1 = P0+P1+P2+P3 + bo + x;  XN = LN(X1, g2, be2).
// ---------------------------------------------------------------------------
__global__ __launch_bounds__(256) void reduce4_ln(
    const u16* __restrict__ P0, const u16* __restrict__ P1,
    const u16* __restrict__ P2, const u16* __restrict__ P3,
    const float* __restrict__ bias, const float* __restrict__ res,
    const float* __restrict__ g, const float* __restrict__ bp,
    float* __restrict__ X1, u16* __restrict__ XN)
{
  const int row = blockIdx.x;
  const int t = threadIdx.x;
  const size_t base = (size_t)row * D_MODEL + t * 4;
  const int col = t * 4;
  uint2 a0 = *(const uint2*)(P0 + base);
  uint2 a1 = *(const uint2*)(P1 + base);
  uint2 a2 = *(const uint2*)(P2 + base);
  uint2 a3 = *(const uint2*)(P3 + base);
  float4 bb = *(const float4*)(bias + col);
  float4 rr = *(const float4*)(res + base);
  float4 y;
  y.x = bflo(a0.x) + bflo(a1.x) + bflo(a2.x) + bflo(a3.x) + bb.x + rr.x;
  y.y = bfhi(a0.x) + bfhi(a1.x) + bfhi(a2.x) + bfhi(a3.x) + bb.y + rr.y;
  y.z = bflo(a0.y) + bflo(a1.y) + bflo(a2.y) + bflo(a3.y) + bb.z + rr.z;
  y.w = bfhi(a0.y) + bfhi(a1.y) + bfhi(a2.y) + bfhi(a3.y) + bb.w + rr.w;
  *(float4*)(X1 + base) = y;

  float s  = y.x + y.y + y.z + y.w;
  float ss = y.x * y.x + y.y * y.y + y.z * y.z + y.w * y.w;
#pragma unroll
  for (int off = 32; off > 0; off >>= 1) {
    s  += __shfl_down(s, off);
    ss += __shfl_down(ss, off);
  }
  __shared__ float sm[4], ssm[4], stat[2];
  if ((t & 63) == 0) { sm[t >> 6] = s; ssm[t >> 6] = ss; }
  __syncthreads();
  if (t == 0) {
    float S = sm[0] + sm[1] + sm[2] + sm[3];
    float SS = ssm[0] + ssm[1] + ssm[2] + ssm[3];
    float mu = S * (1.0f / 1024.0f);
    float var = SS * (1.0f / 1024.0f) - mu * mu;
    stat[0] = mu;
    stat[1] = rsqrtf(fmaxf(var, 0.0f) + 1e-5f);
  }
  __syncthreads();
  const float mu = stat[0], rstd = stat[1];
  float4 gg = *(const float4*)(g + col);
  float4 be = *(const float4*)(bp + col);
  u16 o0 = f2bf((y.x - mu) * rstd * gg.x + be.x);
  u16 o1 = f2bf((y.y - mu) * rstd * gg.y + be.y);
  u16 o2 = f2bf((y.z - mu) * rstd * gg.z + be.z);
  u16 o3 = f2bf((y.w - mu) * rstd * gg.w + be.w);
  uint2 wv;
  wv.x = (u32)o0 | ((u32)o1 << 16);
  wv.y = (u32)o2 | ((u32)o3 << 16);
  *(uint2*)(XN + base) = wv;
}

// ---------------------------------------------------------------------------
// LayerNorm: fp32 in, bf16 out. One block per row (D=1024).
// ---------------------------------------------------------------------------
__global__ __launch_bounds__(256) void ln_kernel(
    const float* __restrict__ x, const float* __restrict__ g,
    const float* __restrict__ b, u16* __restrict__ o)
{
  const int row = blockIdx.x;
  const int t = threadIdx.x;
  float4 v = *(const float4*)(x + (size_t)row * D_MODEL + t * 4);
  float s  = v.x + v.y + v.z + v.w;
  float ss = v.x * v.x + v.y * v.y + v.z * v.z + v.w * v.w;
#pragma unroll
  for (int off = 32; off > 0; off >>= 1) {
    s  += __shfl_down(s, off);
    ss += __shfl_down(ss, off);
  }
  __shared__ float sm[4], ssm[4], stat[2];
  if ((t & 63) == 0) { sm[t >> 6] = s; ssm[t >> 6] = ss; }
  __syncthreads();
  if (t == 0) {
    float S = sm[0] + sm[1] + sm[2] + sm[3];
    float SS = ssm[0] + ssm[1] + ssm[2] + ssm[3];
    float mu = S * (1.0f / 1024.0f);
    float var = SS * (1.0f / 1024.0f) - mu * mu;
    stat[0] = mu;
    stat[1] = rsqrtf(fmaxf(var, 0.0f) + 1e-5f);
  }
  __syncthreads();
  const float mu = stat[0], rstd = stat[1];
  float4 gg = *(const float4*)(g + t * 4);
  float4 bb = *(const float4*)(b + t * 4);
  u16 o0 = f2bf((v.x - mu) * rstd * gg.x + bb.x);
  u16 o1 = f2bf((v.y - mu) * rstd * gg.y + bb.y);
  u16 o2 = f2bf((v.z - mu) * rstd * gg.z + bb.z);
  u16 o3 = f2bf((v.w - mu) * rstd * gg.w + bb.w);
  uint2 w;
  w.x = (u32)o0 | ((u32)o1 << 16);
  w.y = (u32)o2 | ((u32)o3 << 16);
  *(uint2*)(o + (size_t)row * D_MODEL + t * 4) = w;
}

// ---------------------------------------------------------------------------
// Banded attention, MFMA flash style (rounds 4-7 verified).
// ---------------------------------------------------------------------------
__global__ __launch_bounds__(256) void attn_band(
    const u16* __restrict__ qkv, u16* __restrict__ out)
{
  const int t    = threadIdx.x;
  const int w    = t >> 6;
  const int lane = t & 63;
  const int m    = lane & 15;
  const int quad = lane >> 4;
  const int bh   = blockIdx.y;
  const int b    = bh >> 4, h = bh & 15;
  const int i0   = blockIdx.x * 64;
  const size_t bb = (size_t)b * S_LEN;

  __shared__ __attribute__((aligned(16))) u16 Ks[32 * 72];
  __shared__ __attribute__((aligned(16))) u16 Vt[64 * 40];
  __shared__ __attribute__((aligned(16))) u16 Ps[4][16 * 40];

  const u16* qrow = qkv + (bb + i0 + 16 * w + m) * 3072 + h * 64;
  const short8 aq0 = *(const short8*)(qrow + quad * 8);
  const short8 aq1 = *(const short8*)(qrow + 32 + quad * 8);

  f32x4 Ov[4];
#pragma unroll
  for (int td = 0; td < 4; ++td) Ov[td] = (f32x4){0.f, 0.f, 0.f, 0.f};
  float mP[4] = {-1e30f, -1e30f, -1e30f, -1e30f};
  float lS[4] = {0.f, 0.f, 0.f, 0.f};

  const int iB = i0 + 16 * w + quad * 4;

  const int lo = max(32, i0 - 128);
  const int hi = min(S_LEN, i0 + 192);
  const int nChunks = 1 + (hi - lo) / 32;

  const int skr = t >> 3;
  const int skc = (t & 7) * 8;

  for (int c = 0; c < nChunks; ++c) {
    const int j0 = (c == 0) ? 0 : lo + (c - 1) * 32;
    __syncthreads();
    {
      const u16* src = qkv + (bb + j0 + skr) * 3072 + 1024 + h * 64 + skc;
      uint4 kk = *(const uint4*)src;
      uint4 vv = *(const uint4*)(src + 1024);
      *(uint4*)&Ks[skr * 72 + skc] = kk;
      const u16 vs[8] = {
        (u16)(vv.x & 0xffffu), (u16)(vv.x >> 16),
        (u16)(vv.y & 0xffffu), (u16)(vv.y >> 16),
        (u16)(vv.z & 0xffffu), (u16)(vv.z >> 16),
        (u16)(vv.w & 0xffffu), (u16)(vv.w >> 16)};
#pragma unroll
      for (int i = 0; i < 8; ++i) Vt[(skc + i) * 40 + skr] = vs[i];
    }
    __syncthreads();

    const short8 b00 = *(const short8*)&Ks[m * 72 + quad * 8];
    const short8 b01 = *(const short8*)&Ks[m * 72 + 32 + quad * 8];
    const short8 b10 = *(const short8*)&Ks[(16 + m) * 72 + quad * 8];
    const short8 b11 = *(const short8*)&Ks[(16 + m) * 72 + 32 + quad * 8];
    f32x4 s0 = (f32x4){0.f, 0.f, 0.f, 0.f};
    f32x4 s1 = (f32x4){0.f, 0.f, 0.f, 0.f};
    s0 = __builtin_amdgcn_mfma_f32_16x16x32_bf16(aq0, b00, s0, 0, 0, 0);
    s0 = __builtin_amdgcn_mfma_f32_16x16x32_bf16(aq1, b01, s0, 0, 0, 0);
    s1 = __builtin_amdgcn_mfma_f32_16x16x32_bf16(aq0, b10, s1, 0, 0, 0);
    s1 = __builtin_amdgcn_mfma_f32_16x16x32_bf16(aq1, b11, s1, 0, 0, 0);

    const int jA = j0 + m, jB = j0 + 16 + m;
#pragma unroll
    for (int r = 0; r < 4; ++r) {
      const int iG = iB + r;
      const int da = iG - jA, db = iG - jB;
      s0[r] = ((jA < 16) || (da >= -128 && da <= 128)) ? s0[r] * 0.125f : -1e30f;
      s1[r] = ((jB < 16) || (db >= -128 && db <= 128)) ? s1[r] * 0.125f : -1e30f;
    }

    float al[4];
#pragma unroll
    for (int r = 0; r < 4; ++r) {
      float mx = fmaxf(s0[r], s1[r]);
      mx = fmaxf(mx, __shfl_xor(mx, 1, 16));
      mx = fmaxf(mx, __shfl_xor(mx, 2, 16));
      mx = fmaxf(mx, __shfl_xor(mx, 4, 16));
      mx = fmaxf(mx, __shfl_xor(mx, 8, 16));
      const float mn = fmaxf(mP[r], mx);
      al[r] = __expf(mP[r] - mn);
      mP[r] = mn;
      const float p0 = __expf(s0[r] - mn);
      const float p1 = __expf(s1[r] - mn);
      float ps = p0 + p1;
      ps += __shfl_xor(ps, 1, 16);
      ps += __shfl_xor(ps, 2, 16);
      ps += __shfl_xor(ps, 4, 16);
      ps += __shfl_xor(ps, 8, 16);
      lS[r] = lS[r] * al[r] + ps;
      Ps[w][(quad * 4 + r) * 40 + m]      = f2bf(p0);
      Ps[w][(quad * 4 + r) * 40 + 16 + m] = f2bf(p1);
    }
#pragma unroll
    for (int td = 0; td < 4; ++td)
#pragma unroll
      for (int r = 0; r < 4; ++r) Ov[td][r] *= al[r];

    const short8 pa = *(const short8*)&Ps[w][m * 40 + quad * 8];
#pragma unroll
    for (int td = 0; td < 4; ++td) {
      const short8 bv = *(const short8*)&Vt[(td * 16 + m) * 40 + quad * 8];
      Ov[td] = __builtin_amdgcn_mfma_f32_16x16x32_bf16(pa, bv, Ov[td], 0, 0, 0);
    }
  }

  if (i0 + 16 * w >= 16) {
    float inv[4];
#pragma unroll
    for (int r = 0; r < 4; ++r) inv[r] = 1.0f / lS[r];
#pragma unroll
    for (int td = 0; td < 4; ++td)
#pragma unroll
      for (int r = 0; r < 4; ++r)
        out[(bb + iB + r) * 1024 + h * 64 + td * 16 + m] =
            f2bf(Ov[td][r] * inv[r]);
  }
}

// ---------------------------------------------------------------------------
// Global rows (i<16): MFMA split-K partials + combine (round-7 verified).
// ---------------------------------------------------------------------------
__global__ __launch_bounds__(256) void attn_gpart(
    const u16* __restrict__ qkv, float* __restrict__ Obuf,
    float* __restrict__ mbuf, float* __restrict__ lbuf)
{
  const int t    = threadIdx.x;
  const int w    = t >> 6;
  const int lane = t & 63;
  const int m    = lane & 15;
  const int quad = lane >> 4;
  const int kb   = blockIdx.x;   // 0..7
  const int bh   = blockIdx.y;   // 0..31
  const int b    = bh >> 4, h = bh & 15;
  const size_t bb = (size_t)b * S_LEN;

  __shared__ __attribute__((aligned(16))) u16 Ks[4][32 * 72];
  __shared__ __attribute__((aligned(16))) u16 Vt[4][64 * 40];
  __shared__ __attribute__((aligned(16))) u16 Ps[4][16 * 40];

  const u16* qrow = qkv + (bb + m) * 3072 + h * 64;
  const short8 aq0 = *(const short8*)(qrow + quad * 8);
  const short8 aq1 = *(const short8*)(qrow + 32 + quad * 8);

  f32x4 Ov[4];
#pragma unroll
  for (int td = 0; td < 4; ++td) Ov[td] = (f32x4){0.f, 0.f, 0.f, 0.f};
  float mP[4] = {-1e30f, -1e30f, -1e30f, -1e30f};
  float lS[4] = {0.f, 0.f, 0.f, 0.f};

  const int srow = lane >> 1;
  const int sd   = (lane & 1) * 32;

  for (int c = 0; c < 2; ++c) {
    const int j0 = kb * 256 + w * 64 + c * 32;
    {
      const u16* src = qkv + (bb + j0 + srow) * 3072 + 1024 + h * 64 + sd;
      uint4 k0 = *(const uint4*)(src);
      uint4 k1 = *(const uint4*)(src + 8);
      uint4 k2 = *(const uint4*)(src + 16);
      uint4 k3 = *(const uint4*)(src + 24);
      *(uint4*)&Ks[w][srow * 72 + sd]      = k0;
      *(uint4*)&Ks[w][srow * 72 + sd + 8]  = k1;
      *(uint4*)&Ks[w][srow * 72 + sd + 16] = k2;
      *(uint4*)&Ks[w][srow * 72 + sd + 24] = k3;
#pragma unroll
      for (int q4 = 0; q4 < 4; ++q4) {
        uint4 vv = *(const uint4*)(src + 1024 + q4 * 8);
        const u16 vs[8] = {
          (u16)(vv.x & 0xffffu), (u16)(vv.x >> 16),
          (u16)(vv.y & 0xffffu), (u16)(vv.y >> 16),
          (u16)(vv.z & 0xffffu), (u16)(vv.z >> 16),
          (u16)(vv.w & 0xffffu), (u16)(vv.w >> 16)};
#pragma unroll
        for (int i = 0; i < 8; ++i)
          Vt[w][(sd + q4 * 8 + i) * 40 + srow] = vs[i];
      }
    }

    const short8 b00 = *(const short8*)&Ks[w][m * 72 + quad * 8];
    const short8 b01 = *(const short8*)&Ks[w][m * 72 + 32 + quad * 8];
    const short8 b10 = *(const short8*)&Ks[w][(16 + m) * 72 + quad * 8];
    const short8 b11 = *(const short8*)&Ks[w][(16 + m) * 72 + 32 + quad * 8];
    f32x4 s0 = (f32x4){0.f, 0.f, 0.f, 0.f};
    f32x4 s1 = (f32x4){0.f, 0.f, 0.f, 0.f};
    s0 = __builtin_amdgcn_mfma_f32_16x16x32_bf16(aq0, b00, s0, 0, 0, 0);
    s0 = __builtin_amdgcn_mfma_f32_16x16x32_bf16(aq1, b01, s0, 0, 0, 0);
    s1 = __builtin_amdgcn_mfma_f32_16x16x32_bf16(aq0, b10, s1, 0, 0, 0);
    s1 = __builtin_amdgcn_mfma_f32_16x16x32_bf16(aq1, b11, s1, 0, 0, 0);

    float al[4];
#pragma unroll
    for (int r = 0; r < 4; ++r) {
      const float v0 = s0[r] * 0.125f, v1 = s1[r] * 0.125f;
      float mx = fmaxf(v0, v1);
      mx = fmaxf(mx, __shfl_xor(mx, 1, 16));
      mx = fmaxf(mx, __shfl_xor(mx, 2, 16));
      mx = fmaxf(mx, __shfl_xor(mx, 4, 16));
      mx = fmaxf(mx, __shfl_xor(mx, 8, 16));
      const float mn = fmaxf(mP[r], mx);
      al[r] = __expf(mP[r] - mn);
      mP[r] = mn;
      const float p0 = __expf(v0 - mn);
      const float p1 = __expf(v1 - mn);
      float ps = p0 + p1;
      ps += __shfl_xor(ps, 1, 16);
      ps += __shfl_xor(ps, 2, 16);
      ps += __shfl_xor(ps, 4, 16);
      ps += __shfl_xor(ps, 8, 16);
      lS[r] = lS[r] * al[r] + ps;
      Ps[w][(quad * 4 + r) * 40 + m]      = f2bf(p0);
      Ps[w][(quad * 4 + r) * 40 + 16 + m] = f2bf(p1);
    }
#pragma unroll
    for (int td = 0; td < 4; ++td)
#pragma unroll
      for (int r = 0; r < 4; ++r) Ov[td][r] *= al[r];

    const short8 pa = *(const short8*)&Ps[w][m * 40 + quad * 8];
#pragma unroll
    for (int td = 0; td < 4; ++td) {
      const short8 bv = *(const short8*)&Vt[w][(td * 16 + m) * 40 + quad * 8];
      Ov[td] = __builtin_amdgcn_mfma_f32_16x16x32_bf16(pa, bv, Ov[td], 0, 0, 0);
    }
  }

  const int p = kb * 4 + w;
  const size_t ob = ((size_t)(bh * 32 + p)) * 16 * 64;
#pragma unroll
  for (int td = 0; td < 4; ++td)
#pragma unroll
    for (int r = 0; r < 4; ++r)
      Obuf[ob + (size_t)(quad * 4 + r) * 64 + td * 16 + m] = Ov[td][r];
  if (m == 0) {
    const int mb = (bh * 32 + p) * 16;
#pragma unroll
    for (int r = 0; r < 4; ++r) {
      mbuf[mb + quad * 4 + r] = mP[r];
      lbuf[mb + quad * 4 + r] = lS[r];
    }
  }
}

__global__ __launch_bounds__(256) void attn_gcombine(
    const float* __restrict__ Obuf, const float* __restrict__ mbuf,
    const float* __restrict__ lbuf, u16* __restrict__ out)
{
  const int bh = blockIdx.x;  // 0..31
  const int b  = bh >> 4, h = bh & 15;
  const int t  = threadIdx.x;
  const int q  = t >> 4;
  const int d0 = (t & 15) * 4;
  const int mb = bh * 32 * 16;

  float mv[32];
  float M = -1e30f;
#pragma unroll
  for (int p = 0; p < 32; ++p) {
    mv[p] = mbuf[mb + p * 16 + q];
    M = fmaxf(M, mv[p]);
  }
  float L = 0.f;
  float4 acc = {0.f, 0.f, 0.f, 0.f};
#pragma unroll
  for (int p = 0; p < 32; ++p) {
    const float wp = __expf(mv[p] - M);
    L += lbuf[mb + p * 16 + q] * wp;
    float4 o = *(const float4*)&Obuf[(((size_t)(bh * 32 + p)) * 16 + q) * 64 + d0];
    acc.x += wp * o.x; acc.y += wp * o.y;
    acc.z += wp * o.z; acc.w += wp * o.w;
  }
  const float inv = 1.0f / L;
  uint2 wv;
  wv.x = (u32)f2bf(acc.x * inv) | ((u32)f2bf(acc.y * inv) << 16);
  wv.y = (u32)f2bf(acc.z * inv) | ((u32)f2bf(acc.w * inv) << 16);
  *(uint2*)(out + ((size_t)b * S_LEN + q) * 1024 + h * 64 + d0) = wv;
}

// ---------------------------------------------------------------------------
// Consolidated prep: 6 weight transposes (fp32 -> bf16) + bias concat.
// ---------------------------------------------------------------------------
__global__ __launch_bounds__(256) void prep_all(
    const float* __restrict__ Wq, const float* __restrict__ Wk,
    const float* __restrict__ Wv, const float* __restrict__ Wo,
    const float* __restrict__ W1, const float* __restrict__ W2,
    const float* __restrict__ bq, const float* __restrict__ bk,
    const float* __restrict__ bv,
    u16* __restrict__ WQKVT, u16* __restrict__ WOT,
    u16* __restrict__ W1T, u16* __restrict__ W2T,
    float* __restrict__ BQKV)
{
  const int gb = blockIdx.x;
  const int t = threadIdx.x;
  if (gb >= 3072) {  // concat
    const int i = (gb - 3072) * 256 + t;
    if (i < 1024) BQKV[i] = bq[i];
    else if (i < 2048) BQKV[i] = bk[i - 1024];
    else BQKV[i] = bv[i - 2048];
    return;
  }
  const float* in; u16* outp; int R, Cc, bx, by;
  if (gb < 1024) {
    const int seg = gb >> 8, local = gb & 255;
    bx = local & 15; by = local >> 4; R = 1024; Cc = 1024;
    in   = (seg == 0) ? Wq : (seg == 1) ? Wk : (seg == 2) ? Wv : Wo;
    outp = (seg < 3) ? WQKVT + (size_t)seg * 1024 * 1024 : WOT;
  } else if (gb < 2048) {
    const int local = gb - 1024;
    bx = local & 63; by = local >> 6; R = 1024; Cc = 4096;
    in = W1; outp = W1T;
  } else {
    const int local = gb - 2048;
    bx = local & 15; by = local >> 4; R = 4096; Cc = 1024;
    in = W2; outp = W2T;
  }

  __shared__ u16 tile[64][65];
  const int tr = by * 64, tc = bx * 64;
  const int lr = t >> 2, lc0 = (t & 3) * 16;
  const float* src = in + (size_t)(tr + lr) * Cc + tc + lc0;
  float4 a0 = *(const float4*)(src);
  float4 a1 = *(const float4*)(src + 4);
  float4 a2 = *(const float4*)(src + 8);
  float4 a3 = *(const float4*)(src + 12);
  const float vals[16] = {a0.x, a0.y, a0.z, a0.w, a1.x, a1.y, a1.z, a1.w,
                          a2.x, a2.y, a2.z, a2.w, a3.x, a3.y, a3.z, a3.w};
#pragma unroll
  for (int q = 0; q < 16; ++q) tile[lr][lc0 + q] = f2bf(vals[q]);
  __syncthreads();
  u16* dst = outp + (size_t)(tc + lr) * R + tr + lc0;
  u32 w[8];
#pragma unroll
  for (int q = 0; q < 8; ++q)
    w[q] = (u32)tile[lc0 + 2 * q][lr] | ((u32)tile[lc0 + 2 * q + 1][lr] << 16);
  uint4 s0; s0.x = w[0]; s0.y = w[1]; s0.z = w[2]; s0.w = w[3];
  uint4 s1; s1.x = w[4]; s1.y = w[5]; s1.z = w[6]; s1.w = w[7];
  *(uint4*)dst = s0;
  *(uint4*)(dst + 8) = s1;
}

// ---------------------------------------------------------------------------
// workspace layout (bytes) — ~64 MB (validated rounds 3-12).
// ---------------------------------------------------------------------------
static const size_t OFF_WQKVT = 0;                                   // bf16 [3072][1024]
static const size_t OFF_WOT   = OFF_WQKVT + (size_t)3072 * 1024 * 2; // bf16 [1024][1024]
static const size_t OFF_W1T   = OFF_WOT   + (size_t)1024 * 1024 * 2; // bf16 [4096][1024]
static const size_t OFF_W2T   = OFF_W1T   + (size_t)4096 * 1024 * 2; // bf16 [1024][4096]
static const size_t OFF_BQKV  = OFF_W2T   + (size_t)1024 * 4096 * 2; // fp32 [3072]
static const size_t OFF_XN    = OFF_BQKV  + 16384;                   // bf16 [4096][1024]
static const size_t OFF_QKV   = OFF_XN    + (size_t)4096 * 1024 * 2; // bf16 [4096][3072]
static const size_t OFF_AO    = OFF_QKV   + (size_t)4096 * 3072 * 2; // bf16 [4096][1024]
static const size_t OFF_H     = OFF_QKV;  // bf16 [4096][4096], aliases QKV+AO

extern "C" void kernel_launch(void* const* d_in, const int* in_sizes, int n_in,
                              void* d_out, int out_size, void* d_ws, size_t ws_size,
                              hipStream_t stream)
{
  const float* x   = (const float*)d_in[0];
  const float* Wq  = (const float*)d_in[1];
  const float* bq  = (const float*)d_in[2];
  const float* Wk  = (const float*)d_in[3];
  const float* bk  = (const float*)d_in[4];
  const float* Wv  = (const float*)d_in[5];
  const float* bv  = (const float*)d_in[6];
  const float* Wo  = (const float*)d_in[7];
  const float* bo  = (const float*)d_in[8];
  const float* g1  = (const float*)d_in[9];
  const float* be1 = (const float*)d_in[10];
  const float* W1  = (const float*)d_in[11];
  const float* b1  = (const float*)d_in[12];
  const float* W2  = (const float*)d_in[13];
  const float* b2  = (const float*)d_in[14];
  const float* g2  = (const float*)d_in[15];
  const float* be2 = (const float*)d_in[16];
  float* outf = (float*)d_out;
  char* ws = (char*)d_ws;

  u16*   WQKVT = (u16*)(ws + OFF_WQKVT);
  u16*   WOT   = (u16*)(ws + OFF_WOT);
  u16*   W1T   = (u16*)(ws + OFF_W1T);
  u16*   W2T   = (u16*)(ws + OFF_W2T);
  float* BQKV  = (float*)(ws + OFF_BQKV);
  u16*   XN    = (u16*)(ws + OFF_XN);
  u16*   QKV   = (u16*)(ws + OFF_QKV);
  u16*   AO    = (u16*)(ws + OFF_AO);
  u16*   Hbuf  = (u16*)(ws + OFF_H);
  float* X1    = outf;  // fp32 residual stream #2 lives in d_out
  // Wo split-K4 partials
  u16* PWo0 = (u16*)(ws + OFF_QKV);
  u16* PWo1 = PWo0 + (size_t)4096 * 1024;
  u16* PWo2 = PWo1 + (size_t)4096 * 1024;
  u16* PWo3 = (u16*)(ws + OFF_XN);
  // W2 split-K2 partials
  u16* PW20 = (u16*)(ws + OFF_W1T);
  u16* PW21 = (u16*)(ws + OFF_XN);
  float* GO = (float*)(ws + OFF_XN);
  float* GM = GO + (size_t)32 * 32 * 16 * 64;
  float* GL = GM + 32 * 32 * 16;

  const dim3 blk(256);
  const dim3 blk512(512);
  prep_all<<<dim3(3084), blk, 0, stream>>>(Wq, Wk, Wv, Wo, W1, W2, bq, bk, bv,
                                           WQKVT, WOT, W1T, W2T, BQKV);

  // attention sublayer
  ln_kernel<<<dim3(ROWS), blk, 0, stream>>>(x, g1, be1, XN);
  gemm256<0, 1024, 1024><<<dim3(12, 16, 1), blk512, 0, stream>>>(
      XN, WQKVT, BQKV, QKV, QKV, QKV, QKV, 3072);
  attn_band<<<dim3(32, 32), blk, 0, stream>>>(QKV, AO);
  attn_gpart<<<dim3(8, 32), blk, 0, stream>>>(QKV, GO, GM, GL);
  attn_gcombine<<<dim3(32), blk, 0, stream>>>(GO, GM, GL, AO);
  gemm256<2, 256, 1024><<<dim3(4, 16, 4), blk512, 0, stream>>>(
      AO, WOT, nullptr, PWo0, PWo1, PWo2, PWo3, 1024);
  // fused: X1 = sum(partials)+bo+x ; XN = LN2(X1)
  reduce4_ln<<<dim3(ROWS), blk, 0, stream>>>(PWo0, PWo1, PWo2, PWo3,
                                             bo, x, g2, be2, X1, XN);

  // FFN sublayer
  gemm256<1, 1024, 1024><<<dim3(16, 16, 1), blk512, 0, stream>>>(
      XN, W1T, b1, Hbuf, Hbuf, Hbuf, Hbuf, 4096);
  gemm256<2, 2048, 4096><<<dim3(4, 16, 2), blk512, 0, stream>>>(
      Hbuf, W2T, nullptr, PW20, PW21, PW21, PW21, 1024);
  reduce2<<<dim3(2048), blk, 0, stream>>>(PW20, PW21, b2, X1, outf);
}

// Round 7
// 345.097 us; speedup vs baseline: 1.0805x; 1.0805x over previous
//
#include <hip/hip_runtime.h>
#include <stdint.h>

// ---------------------------------------------------------------------------
// EncoderBlock: pre-norm transformer block, MI355X (gfx950).
// External dtype: FP32. Internal: bf16 MFMA, fp32 accum, fp32 residual.
// B=2 S=2048 D=1024 H=16 DK=64 DFF=4096 WINDOW=128 GLOBAL=16
// Round 14: v5 reverted (W2 FETCH 2x + pathological dispatch). Engine back
// to v3 (round-10-proven: derived-waits 8-phase + SB0, 53.5us W1), with K
// made runtime (kc0/Ktot args) to allow asymmetric split-K. New: W2 moves
// split-K2 -> split-K3 (1536/1536/1024; 128 -> 192 blocks, critical path
// 32 -> 24 K-tiles). Partials: W1T / XN / (WQKVT+WOT @ ws+0), all dead by
// then. reduce3 folds them + b2 + X1 -> out. Wo-K4 + reduce4_ln kept.
// ---------------------------------------------------------------------------

typedef unsigned short u16;
typedef unsigned int   u32;
typedef __attribute__((ext_vector_type(8))) short  short8;  // 8 bf16 (4 VGPRs)
typedef __attribute__((ext_vector_type(4))) float  f32x4;

#define S_LEN   2048
#define D_MODEL 1024
#define ROWS    4096   // B*S

__device__ __forceinline__ float bf2f(u16 u) {
  union { u32 i; float f; } v; v.i = ((u32)u) << 16; return v.f;
}
__device__ __forceinline__ float bflo(u32 u) {
  union { u32 i; float f; } v; v.i = u << 16; return v.f;
}
__device__ __forceinline__ float bfhi(u32 u) {
  union { u32 i; float f; } v; v.i = u & 0xffff0000u; return v.f;
}
__device__ __forceinline__ u16 f2bf(float f) {
  union { float f; u32 i; } v; v.f = f;
  u32 r = v.i + 0x7fffu + ((v.i >> 16) & 1u);
  return (u16)(r >> 16);
}

// Direct global->LDS copy, 16B/lane (m97). Lands at wave base + lane*16.
__device__ __forceinline__ void gld_lds16(const u16* g, u16* l) {
  __attribute__((address_space(3))) u32* lp =
      reinterpret_cast<__attribute__((address_space(3))) u32*>(
          reinterpret_cast<uintptr_t>(l));
  const __attribute__((address_space(1))) u32* gp =
      reinterpret_cast<const __attribute__((address_space(1))) u32*>(
          reinterpret_cast<uintptr_t>(g));
  __builtin_amdgcn_global_load_lds(gp, lp, 16, 0, 0);
}

// ---------------------------------------------------------------------------
// gemm256 v3 (round-10, verified): 256x256 tile, BK=64, 512 threads
// (8 waves, 2M x 4N). Derived-waits 8-phase schedule + sched_barrier(0)
// pin after each wait. LDS: A/B each [buf 2][khalf 2][256 rows x 32 elems],
// k-chunk rotate swizzle (bank-conflict free, SQ_LDS_BANK_CONFLICT=0).
// K-slice now runtime: slice kz covers [kz*kc0, min((kz+1)*kc0, Ktot)).
// EPI: 0 = bias, 1 = bias+gelu, 2 = raw bf16 partial (split-K via grid.z).
// ---------------------------------------------------------------------------

#define GBAR  asm volatile("s_barrier" ::: "memory")
#define LGKM(n) asm volatile("s_waitcnt lgkmcnt(" #n ")" ::: "memory")
#define VM(n)   asm volatile("s_waitcnt vmcnt(" #n ")" ::: "memory")
#define SB0   __builtin_amdgcn_sched_barrier(0)

#define STAGE_A(buf, t, hm) do {                                              \
    gld_lds16(pA##hm + (size_t)(t) * 64,      &Ald[buf][0][(hm)*4096 + ldst]);\
    gld_lds16(pA##hm + (size_t)(t) * 64 + 32, &Ald[buf][1][(hm)*4096 + ldst]);\
  } while (0)

#define STAGE_B(buf, t, hm) do {                                              \
    gld_lds16(pB##hm + (size_t)(t) * 64,      &Bld[buf][0][(hm)*4096 + ldst]);\
    gld_lds16(pB##hm + (size_t)(t) * 64 + 32, &Bld[buf][1][(hm)*4096 + ldst]);\
  } while (0)

#define READ_B(buf) do {                                                      \
    _Pragma("unroll") for (int nj = 0; nj < 4; ++nj) {                        \
      bfv[nj][0] = *(const short8*)&Bld[buf][0][brow + nj * 512];             \
      bfv[nj][1] = *(const short8*)&Bld[buf][1][brow + nj * 512]; }           \
  } while (0)

// READ_A(buf,q): prefetch quadrant q fragments into af[q&1] (ping-pong).
#define READ_A(buf, q) do {                                                   \
    af[(q)&1][0][0] = *(const short8*)&Ald[buf][0][arow + (2*(q)) * 512];     \
    af[(q)&1][0][1] = *(const short8*)&Ald[buf][1][arow + (2*(q)) * 512];     \
    af[(q)&1][1][0] = *(const short8*)&Ald[buf][0][arow + (2*(q)+1) * 512];   \
    af[(q)&1][1][1] = *(const short8*)&Ald[buf][1][arow + (2*(q)+1) * 512];   \
  } while (0)

#define MFMA_Q(q) do {                                                        \
    __builtin_amdgcn_s_setprio(1);                                            \
    _Pragma("unroll") for (int dm = 0; dm < 2; ++dm)                          \
    _Pragma("unroll") for (int kk = 0; kk < 2; ++kk)                          \
    _Pragma("unroll") for (int nj = 0; nj < 4; ++nj)                          \
      acc[2*(q)+dm][nj] = __builtin_amdgcn_mfma_f32_16x16x32_bf16(            \
          af[(q)&1][dm][kk], bfv[nj][kk], acc[2*(q)+dm][nj], 0, 0, 0);        \
    __builtin_amdgcn_s_setprio(0);                                            \
  } while (0)

template <int EPI, int LDK>
__global__ __launch_bounds__(512) void gemm256(
    const u16* __restrict__ A, const u16* __restrict__ Bt,
    const float* __restrict__ bias, u16* __restrict__ C0,
    u16* __restrict__ C1, u16* __restrict__ C2, u16* __restrict__ C3,
    int N, int kc0, int Ktot)
{
  __shared__ __attribute__((aligned(16))) u16 Ald[2][2][256 * 32];
  __shared__ __attribute__((aligned(16))) u16 Bld[2][2][256 * 32];

  const int tid  = threadIdx.x;
  const int w    = tid >> 6;
  const int lane = tid & 63;
  const int wm   = w >> 2;       // 0..1  (M half)
  const int wn   = w & 3;        // 0..3  (N quarter)
  const int lm   = lane & 15;
  const int kq   = lane >> 4;
  const int bm   = blockIdx.y * 256;
  const int bn   = blockIdx.x * 256;
  const int kz   = blockIdx.z;

  const int koff = kz * kc0;
  const int kc   = min(kc0, Ktot - koff);
  const int P    = kc >> 7;   // pair count (2 K-tiles of 64); kc % 128 == 0

  const u16* Ak = A  + (size_t)koff;
  const u16* Bk = Bt + (size_t)koff;
  u16* C = (kz == 0) ? C0 : (kz == 1) ? C1 : (kz == 2) ? C2 : C3;

  // read-side swizzled chunk slot (row bases are multiples of 16).
  const int rslot = ((kq + (lm >> 1)) & 3) * 8;
  const int arow  = (wm * 128 + lm) * 32 + rslot;   // + mi*512
  const int brow  = (wn * 64  + lm) * 32 + rslot;   // + nj*512

  // stage-side: lane covers row (lane>>2), LDS chunk slot (lane&3).
  const int gcoff = (((lane & 3) - (lane >> 3)) & 3) * 8;
  const int srow  = w * 16 + (lane >> 2);           // row within 128-half
  const int ldst  = w * 512;                        // wave LDS base (u16)

  const u16* pA0 = Ak + (size_t)(bm + srow) * LDK + gcoff;
  const u16* pA1 = pA0 + (size_t)128 * LDK;
  const u16* pB0 = Bk + (size_t)(bn + srow) * LDK + gcoff;
  const u16* pB1 = pB0 + (size_t)128 * LDK;

  f32x4 acc[8][4];
#pragma unroll
  for (int i = 0; i < 8; ++i)
#pragma unroll
    for (int j = 0; j < 4; ++j) acc[i][j] = (f32x4){0.f, 0.f, 0.f, 0.f};

  short8 af[2][2][2];   // [parity][dm][khalf]
  short8 bfv[4][2];

  // prologue: tile0 (A+B) + tile1.B staged; vmcnt(4) keeps t1.B in flight.
  STAGE_B(0, 0, 0); STAGE_B(0, 0, 1);
  STAGE_A(0, 0, 0); STAGE_A(0, 0, 1);
  STAGE_B(1, 1, 0); STAGE_B(1, 1, 1);
  VM(4);
  GBAR;
  READ_A(0, 0);   // prefetch q0 for first MFMA

#pragma unroll 1
  for (int i = 0; i < P - 1; ++i) {
    const int t1 = 2 * i + 1, t2 = 2 * i + 2, t3 = 2 * i + 3;
    GBAR; STAGE_A(1, t1, 0); READ_B(0); READ_A(0, 1); LGKM(4); SB0; MFMA_Q(0);
    GBAR; STAGE_A(1, t1, 1); READ_A(0, 2);            LGKM(4); SB0; MFMA_Q(1);
    GBAR; STAGE_B(0, t2, 0); READ_A(0, 3);            LGKM(4); SB0; MFMA_Q(2);
    VM(2);
    GBAR; STAGE_B(0, t2, 1); READ_A(1, 0);            LGKM(4); SB0; MFMA_Q(3);
    GBAR; STAGE_A(0, t2, 0); READ_B(1); READ_A(1, 1); LGKM(4); SB0; MFMA_Q(0);
    GBAR; STAGE_A(0, t2, 1); READ_A(1, 2);            LGKM(4); SB0; MFMA_Q(1);
    GBAR; STAGE_B(1, t3, 0); READ_A(1, 3);            LGKM(4); SB0; MFMA_Q(2);
    VM(2);
    GBAR; STAGE_B(1, t3, 1); READ_A(0, 0);            LGKM(4); SB0; MFMA_Q(3);
  }
  {  // final pair: tile (2P-2) in buf0, (2P-1) in buf1 (B already staged).
    const int t1 = 2 * P - 1;
    GBAR; STAGE_A(1, t1, 0); READ_B(0); READ_A(0, 1); LGKM(4); SB0; MFMA_Q(0);
    GBAR; STAGE_A(1, t1, 1); READ_A(0, 2);            LGKM(4); SB0; MFMA_Q(1);
    GBAR;                    READ_A(0, 3);            LGKM(4); SB0; MFMA_Q(2);
    VM(0);
    GBAR;                    READ_A(1, 0);            LGKM(4); SB0; MFMA_Q(3);
    GBAR;                    READ_B(1); READ_A(1, 1); LGKM(4); SB0; MFMA_Q(0);
    GBAR;                    READ_A(1, 2);            LGKM(4); SB0; MFMA_Q(1);
    GBAR;                    READ_A(1, 3);            LGKM(4); SB0; MFMA_Q(2);
    LGKM(0); SB0; MFMA_Q(3);
  }

  const int r0 = kq * 4;
#pragma unroll
  for (int mi = 0; mi < 8; ++mi) {
#pragma unroll
    for (int r = 0; r < 4; ++r) {
      const int grow = bm + wm * 128 + mi * 16 + r0 + r;
#pragma unroll
      for (int nj = 0; nj < 4; ++nj) {
        const int gcol = bn + wn * 64 + nj * 16 + lm;
        float v = acc[mi][nj][r];
        if (EPI < 2) v += bias[gcol];
        if (EPI == 1) v = 0.5f * v * (1.0f + erff(v * 0.70710678118654752f));
        C[(size_t)grow * N + gcol] = f2bf(v);
      }
    }
  }
}

// out[idx] = P0+P1+P2 + bias[col] + res[idx]   (N fixed = 1024)
__global__ __launch_bounds__(256) void reduce3(
    const u16* __restrict__ P0, const u16* __restrict__ P1,
    const u16* __restrict__ P2,
    const float* __restrict__ bias, const float* res, float* out)
{
  const size_t base = ((size_t)blockIdx.x * 256 + threadIdx.x) * 8;
  const int col = (int)(base & 1023);
  uint4 p0 = *(const uint4*)(P0 + base);
  uint4 p1 = *(const uint4*)(P1 + base);
  uint4 p2 = *(const uint4*)(P2 + base);
  float4 b0 = *(const float4*)(bias + col);
  float4 b1 = *(const float4*)(bias + col + 4);
  float4 r0 = *(const float4*)(res + base);
  float4 r1 = *(const float4*)(res + base + 4);
  float4 o0, o1;
  o0.x = bflo(p0.x) + bflo(p1.x) + bflo(p2.x) + b0.x + r0.x;
  o0.y = bfhi(p0.x) + bfhi(p1.x) + bfhi(p2.x) + b0.y + r0.y;
  o0.z = bflo(p0.y) + bflo(p1.y) + bflo(p2.y) + b0.z + r0.z;
  o0.w = bfhi(p0.y) + bfhi(p1.y) + bfhi(p2.y) + b0.w + r0.w;
  o1.x = bflo(p0.z) + bflo(p1.z) + bflo(p2.z) + b1.x + r1.x;
  o1.y = bfhi(p0.z) + bfhi(p1.z) + bfhi(p2.z) + b1.y + r1.y;
  o1.z = bflo(p0.w) + bflo(p1.w) + bflo(p2.w) + b1.z + r1.z;
  o1.w = bfhi(p0.w) + bfhi(p1.w) + bfhi(p2.w) + b1.w + r1.w;
  *(float4*)(out + base) = o0;
  *(float4*)(out + base + 4) = o1;
}

// ---------------------------------------------------------------------------
// Fused Wo-boundary: X1 = P0+P1+P2+P3 + bo + x;  XN = LN(X1, g2, be2).
// ---------------------------------------------------------------------------
__global__ __launch_bounds__(256) void reduce4_ln(
    const u16* __restrict__ P0, const u16* __restrict__ P1,
    const u16* __restrict__ P2, const u16* __restrict__ P3,
    const float* __restrict__ bias, const float* __restrict__ res,
    const float* __restrict__ g, const float* __restrict__ bp,
    float* __restrict__ X1, u16* __restrict__ XN)
{
  const int row = blockIdx.x;
  const int t = threadIdx.x;
  const size_t base = (size_t)row * D_MODEL + t * 4;
  const int col = t * 4;
  uint2 a0 = *(const uint2*)(P0 + base);
  uint2 a1 = *(const uint2*)(P1 + base);
  uint2 a2 = *(const uint2*)(P2 + base);
  uint2 a3 = *(const uint2*)(P3 + base);
  float4 bb = *(const float4*)(bias + col);
  float4 rr = *(const float4*)(res + base);
  float4 y;
  y.x = bflo(a0.x) + bflo(a1.x) + bflo(a2.x) + bflo(a3.x) + bb.x + rr.x;
  y.y = bfhi(a0.x) + bfhi(a1.x) + bfhi(a2.x) + bfhi(a3.x) + bb.y + rr.y;
  y.z = bflo(a0.y) + bflo(a1.y) + bflo(a2.y) + bflo(a3.y) + bb.z + rr.z;
  y.w = bfhi(a0.y) + bfhi(a1.y) + bfhi(a2.y) + bfhi(a3.y) + bb.w + rr.w;
  *(float4*)(X1 + base) = y;

  float s  = y.x + y.y + y.z + y.w;
  float ss = y.x * y.x + y.y * y.y + y.z * y.z + y.w * y.w;
#pragma unroll
  for (int off = 32; off > 0; off >>= 1) {
    s  += __shfl_down(s, off);
    ss += __shfl_down(ss, off);
  }
  __shared__ float sm[4], ssm[4], stat[2];
  if ((t & 63) == 0) { sm[t >> 6] = s; ssm[t >> 6] = ss; }
  __syncthreads();
  if (t == 0) {
    float S = sm[0] + sm[1] + sm[2] + sm[3];
    float SS = ssm[0] + ssm[1] + ssm[2] + ssm[3];
    float mu = S * (1.0f / 1024.0f);
    float var = SS * (1.0f / 1024.0f) - mu * mu;
    stat[0] = mu;
    stat[1] = rsqrtf(fmaxf(var, 0.0f) + 1e-5f);
  }
  __syncthreads();
  const float mu = stat[0], rstd = stat[1];
  float4 gg = *(const float4*)(g + col);
  float4 be = *(const float4*)(bp + col);
  u16 o0 = f2bf((y.x - mu) * rstd * gg.x + be.x);
  u16 o1 = f2bf((y.y - mu) * rstd * gg.y + be.y);
  u16 o2 = f2bf((y.z - mu) * rstd * gg.z + be.z);
  u16 o3 = f2bf((y.w - mu) * rstd * gg.w + be.w);
  uint2 wv;
  wv.x = (u32)o0 | ((u32)o1 << 16);
  wv.y = (u32)o2 | ((u32)o3 << 16);
  *(uint2*)(XN + base) = wv;
}

// ---------------------------------------------------------------------------
// LayerNorm: fp32 in, bf16 out. One block per row (D=1024).
// ---------------------------------------------------------------------------
__global__ __launch_bounds__(256) void ln_kernel(
    const float* __restrict__ x, const float* __restrict__ g,
    const float* __restrict__ b, u16* __restrict__ o)
{
  const int row = blockIdx.x;
  const int t = threadIdx.x;
  float4 v = *(const float4*)(x + (size_t)row * D_MODEL + t * 4);
  float s  = v.x + v.y + v.z + v.w;
  float ss = v.x * v.x + v.y * v.y + v.z * v.z + v.w * v.w;
#pragma unroll
  for (int off = 32; off > 0; off >>= 1) {
    s  += __shfl_down(s, off);
    ss += __shfl_down(ss, off);
  }
  __shared__ float sm[4], ssm[4], stat[2];
  if ((t & 63) == 0) { sm[t >> 6] = s; ssm[t >> 6] = ss; }
  __syncthreads();
  if (t == 0) {
    float S = sm[0] + sm[1] + sm[2] + sm[3];
    float SS = ssm[0] + ssm[1] + ssm[2] + ssm[3];
    float mu = S * (1.0f / 1024.0f);
    float var = SS * (1.0f / 1024.0f) - mu * mu;
    stat[0] = mu;
    stat[1] = rsqrtf(fmaxf(var, 0.0f) + 1e-5f);
  }
  __syncthreads();
  const float mu = stat[0], rstd = stat[1];
  float4 gg = *(const float4*)(g + t * 4);
  float4 bb = *(const float4*)(b + t * 4);
  u16 o0 = f2bf((v.x - mu) * rstd * gg.x + bb.x);
  u16 o1 = f2bf((v.y - mu) * rstd * gg.y + bb.y);
  u16 o2 = f2bf((v.z - mu) * rstd * gg.z + bb.z);
  u16 o3 = f2bf((v.w - mu) * rstd * gg.w + bb.w);
  uint2 w;
  w.x = (u32)o0 | ((u32)o1 << 16);
  w.y = (u32)o2 | ((u32)o3 << 16);
  *(uint2*)(o + (size_t)row * D_MODEL + t * 4) = w;
}

// ---------------------------------------------------------------------------
// Banded attention, MFMA flash style (rounds 4-7 verified).
// ---------------------------------------------------------------------------
__global__ __launch_bounds__(256) void attn_band(
    const u16* __restrict__ qkv, u16* __restrict__ out)
{
  const int t    = threadIdx.x;
  const int w    = t >> 6;
  const int lane = t & 63;
  const int m    = lane & 15;
  const int quad = lane >> 4;
  const int bh   = blockIdx.y;
  const int b    = bh >> 4, h = bh & 15;
  const int i0   = blockIdx.x * 64;
  const size_t bb = (size_t)b * S_LEN;

  __shared__ __attribute__((aligned(16))) u16 Ks[32 * 72];
  __shared__ __attribute__((aligned(16))) u16 Vt[64 * 40];
  __shared__ __attribute__((aligned(16))) u16 Ps[4][16 * 40];

  const u16* qrow = qkv + (bb + i0 + 16 * w + m) * 3072 + h * 64;
  const short8 aq0 = *(const short8*)(qrow + quad * 8);
  const short8 aq1 = *(const short8*)(qrow + 32 + quad * 8);

  f32x4 Ov[4];
#pragma unroll
  for (int td = 0; td < 4; ++td) Ov[td] = (f32x4){0.f, 0.f, 0.f, 0.f};
  float mP[4] = {-1e30f, -1e30f, -1e30f, -1e30f};
  float lS[4] = {0.f, 0.f, 0.f, 0.f};

  const int iB = i0 + 16 * w + quad * 4;

  const int lo = max(32, i0 - 128);
  const int hi = min(S_LEN, i0 + 192);
  const int nChunks = 1 + (hi - lo) / 32;

  const int skr = t >> 3;
  const int skc = (t & 7) * 8;

  for (int c = 0; c < nChunks; ++c) {
    const int j0 = (c == 0) ? 0 : lo + (c - 1) * 32;
    __syncthreads();
    {
      const u16* src = qkv + (bb + j0 + skr) * 3072 + 1024 + h * 64 + skc;
      uint4 kk = *(const uint4*)src;
      uint4 vv = *(const uint4*)(src + 1024);
      *(uint4*)&Ks[skr * 72 + skc] = kk;
      const u16 vs[8] = {
        (u16)(vv.x & 0xffffu), (u16)(vv.x >> 16),
        (u16)(vv.y & 0xffffu), (u16)(vv.y >> 16),
        (u16)(vv.z & 0xffffu), (u16)(vv.z >> 16),
        (u16)(vv.w & 0xffffu), (u16)(vv.w >> 16)};
#pragma unroll
      for (int i = 0; i < 8; ++i) Vt[(skc + i) * 40 + skr] = vs[i];
    }
    __syncthreads();

    const short8 b00 = *(const short8*)&Ks[m * 72 + quad * 8];
    const short8 b01 = *(const short8*)&Ks[m * 72 + 32 + quad * 8];
    const short8 b10 = *(const short8*)&Ks[(16 + m) * 72 + quad * 8];
    const short8 b11 = *(const short8*)&Ks[(16 + m) * 72 + 32 + quad * 8];
    f32x4 s0 = (f32x4){0.f, 0.f, 0.f, 0.f};
    f32x4 s1 = (f32x4){0.f, 0.f, 0.f, 0.f};
    s0 = __builtin_amdgcn_mfma_f32_16x16x32_bf16(aq0, b00, s0, 0, 0, 0);
    s0 = __builtin_amdgcn_mfma_f32_16x16x32_bf16(aq1, b01, s0, 0, 0, 0);
    s1 = __builtin_amdgcn_mfma_f32_16x16x32_bf16(aq0, b10, s1, 0, 0, 0);
    s1 = __builtin_amdgcn_mfma_f32_16x16x32_bf16(aq1, b11, s1, 0, 0, 0);

    const int jA = j0 + m, jB = j0 + 16 + m;
#pragma unroll
    for (int r = 0; r < 4; ++r) {
      const int iG = iB + r;
      const int da = iG - jA, db = iG - jB;
      s0[r] = ((jA < 16) || (da >= -128 && da <= 128)) ? s0[r] * 0.125f : -1e30f;
      s1[r] = ((jB < 16) || (db >= -128 && db <= 128)) ? s1[r] * 0.125f : -1e30f;
    }

    float al[4];
#pragma unroll
    for (int r = 0; r < 4; ++r) {
      float mx = fmaxf(s0[r], s1[r]);
      mx = fmaxf(mx, __shfl_xor(mx, 1, 16));
      mx = fmaxf(mx, __shfl_xor(mx, 2, 16));
      mx = fmaxf(mx, __shfl_xor(mx, 4, 16));
      mx = fmaxf(mx, __shfl_xor(mx, 8, 16));
      const float mn = fmaxf(mP[r], mx);
      al[r] = __expf(mP[r] - mn);
      mP[r] = mn;
      const float p0 = __expf(s0[r] - mn);
      const float p1 = __expf(s1[r] - mn);
      float ps = p0 + p1;
      ps += __shfl_xor(ps, 1, 16);
      ps += __shfl_xor(ps, 2, 16);
      ps += __shfl_xor(ps, 4, 16);
      ps += __shfl_xor(ps, 8, 16);
      lS[r] = lS[r] * al[r] + ps;
      Ps[w][(quad * 4 + r) * 40 + m]      = f2bf(p0);
      Ps[w][(quad * 4 + r) * 40 + 16 + m] = f2bf(p1);
    }
#pragma unroll
    for (int td = 0; td < 4; ++td)
#pragma unroll
      for (int r = 0; r < 4; ++r) Ov[td][r] *= al[r];

    const short8 pa = *(const short8*)&Ps[w][m * 40 + quad * 8];
#pragma unroll
    for (int td = 0; td < 4; ++td) {
      const short8 bv = *(const short8*)&Vt[(td * 16 + m) * 40 + quad * 8];
      Ov[td] = __builtin_amdgcn_mfma_f32_16x16x32_bf16(pa, bv, Ov[td], 0, 0, 0);
    }
  }

  if (i0 + 16 * w >= 16) {
    float inv[4];
#pragma unroll
    for (int r = 0; r < 4; ++r) inv[r] = 1.0f / lS[r];
#pragma unroll
    for (int td = 0; td < 4; ++td)
#pragma unroll
      for (int r = 0; r < 4; ++r)
        out[(bb + iB + r) * 1024 + h * 64 + td * 16 + m] =
            f2bf(Ov[td][r] * inv[r]);
  }
}

// ---------------------------------------------------------------------------
// Global rows (i<16): MFMA split-K partials + combine (round-7 verified).
// ---------------------------------------------------------------------------
__global__ __launch_bounds__(256) void attn_gpart(
    const u16* __restrict__ qkv, float* __restrict__ Obuf,
    float* __restrict__ mbuf, float* __restrict__ lbuf)
{
  const int t    = threadIdx.x;
  const int w    = t >> 6;
  const int lane = t & 63;
  const int m    = lane & 15;
  const int quad = lane >> 4;
  const int kb   = blockIdx.x;   // 0..7
  const int bh   = blockIdx.y;   // 0..31
  const int b    = bh >> 4, h = bh & 15;
  const size_t bb = (size_t)b * S_LEN;

  __shared__ __attribute__((aligned(16))) u16 Ks[4][32 * 72];
  __shared__ __attribute__((aligned(16))) u16 Vt[4][64 * 40];
  __shared__ __attribute__((aligned(16))) u16 Ps[4][16 * 40];

  const u16* qrow = qkv + (bb + m) * 3072 + h * 64;
  const short8 aq0 = *(const short8*)(qrow + quad * 8);
  const short8 aq1 = *(const short8*)(qrow + 32 + quad * 8);

  f32x4 Ov[4];
#pragma unroll
  for (int td = 0; td < 4; ++td) Ov[td] = (f32x4){0.f, 0.f, 0.f, 0.f};
  float mP[4] = {-1e30f, -1e30f, -1e30f, -1e30f};
  float lS[4] = {0.f, 0.f, 0.f, 0.f};

  const int srow = lane >> 1;
  const int sd   = (lane & 1) * 32;

  for (int c = 0; c < 2; ++c) {
    const int j0 = kb * 256 + w * 64 + c * 32;
    {
      const u16* src = qkv + (bb + j0 + srow) * 3072 + 1024 + h * 64 + sd;
      uint4 k0 = *(const uint4*)(src);
      uint4 k1 = *(const uint4*)(src + 8);
      uint4 k2 = *(const uint4*)(src + 16);
      uint4 k3 = *(const uint4*)(src + 24);
      *(uint4*)&Ks[w][srow * 72 + sd]      = k0;
      *(uint4*)&Ks[w][srow * 72 + sd + 8]  = k1;
      *(uint4*)&Ks[w][srow * 72 + sd + 16] = k2;
      *(uint4*)&Ks[w][srow * 72 + sd + 24] = k3;
#pragma unroll
      for (int q4 = 0; q4 < 4; ++q4) {
        uint4 vv = *(const uint4*)(src + 1024 + q4 * 8);
        const u16 vs[8] = {
          (u16)(vv.x & 0xffffu), (u16)(vv.x >> 16),
          (u16)(vv.y & 0xffffu), (u16)(vv.y >> 16),
          (u16)(vv.z & 0xffffu), (u16)(vv.z >> 16),
          (u16)(vv.w & 0xffffu), (u16)(vv.w >> 16)};
#pragma unroll
        for (int i = 0; i < 8; ++i)
          Vt[w][(sd + q4 * 8 + i) * 40 + srow] = vs[i];
      }
    }

    const short8 b00 = *(const short8*)&Ks[w][m * 72 + quad * 8];
    const short8 b01 = *(const short8*)&Ks[w][m * 72 + 32 + quad * 8];
    const short8 b10 = *(const short8*)&Ks[w][(16 + m) * 72 + quad * 8];
    const short8 b11 = *(const short8*)&Ks[w][(16 + m) * 72 + 32 + quad * 8];
    f32x4 s0 = (f32x4){0.f, 0.f, 0.f, 0.f};
    f32x4 s1 = (f32x4){0.f, 0.f, 0.f, 0.f};
    s0 = __builtin_amdgcn_mfma_f32_16x16x32_bf16(aq0, b00, s0, 0, 0, 0);
    s0 = __builtin_amdgcn_mfma_f32_16x16x32_bf16(aq1, b01, s0, 0, 0, 0);
    s1 = __builtin_amdgcn_mfma_f32_16x16x32_bf16(aq0, b10, s1, 0, 0, 0);
    s1 = __builtin_amdgcn_mfma_f32_16x16x32_bf16(aq1, b11, s1, 0, 0, 0);

    float al[4];
#pragma unroll
    for (int r = 0; r < 4; ++r) {
      const float v0 = s0[r] * 0.125f, v1 = s1[r] * 0.125f;
      float mx = fmaxf(v0, v1);
      mx = fmaxf(mx, __shfl_xor(mx, 1, 16));
      mx = fmaxf(mx, __shfl_xor(mx, 2, 16));
      mx = fmaxf(mx, __shfl_xor(mx, 4, 16));
      mx = fmaxf(mx, __shfl_xor(mx, 8, 16));
      const float mn = fmaxf(mP[r], mx);
      al[r] = __expf(mP[r] - mn);
      mP[r] = mn;
      const float p0 = __expf(v0 - mn);
      const float p1 = __expf(v1 - mn);
      float ps = p0 + p1;
      ps += __shfl_xor(ps, 1, 16);
      ps += __shfl_xor(ps, 2, 16);
      ps += __shfl_xor(ps, 4, 16);
      ps += __shfl_xor(ps, 8, 16);
      lS[r] = lS[r] * al[r] + ps;
      Ps[w][(quad * 4 + r) * 40 + m]      = f2bf(p0);
      Ps[w][(quad * 4 + r) * 40 + 16 + m] = f2bf(p1);
    }
#pragma unroll
    for (int td = 0; td < 4; ++td)
#pragma unroll
      for (int r = 0; r < 4; ++r) Ov[td][r] *= al[r];

    const short8 pa = *(const short8*)&Ps[w][m * 40 + quad * 8];
#pragma unroll
    for (int td = 0; td < 4; ++td) {
      const short8 bv = *(const short8*)&Vt[w][(td * 16 + m) * 40 + quad * 8];
      Ov[td] = __builtin_amdgcn_mfma_f32_16x16x32_bf16(pa, bv, Ov[td], 0, 0, 0);
    }
  }

  const int p = kb * 4 + w;
  const size_t ob = ((size_t)(bh * 32 + p)) * 16 * 64;
#pragma unroll
  for (int td = 0; td < 4; ++td)
#pragma unroll
    for (int r = 0; r < 4; ++r)
      Obuf[ob + (size_t)(quad * 4 + r) * 64 + td * 16 + m] = Ov[td][r];
  if (m == 0) {
    const int mb = (bh * 32 + p) * 16;
#pragma unroll
    for (int r = 0; r < 4; ++r) {
      mbuf[mb + quad * 4 + r] = mP[r];
      lbuf[mb + quad * 4 + r] = lS[r];
    }
  }
}

__global__ __launch_bounds__(256) void attn_gcombine(
    const float* __restrict__ Obuf, const float* __restrict__ mbuf,
    const float* __restrict__ lbuf, u16* __restrict__ out)
{
  const int bh = blockIdx.x;  // 0..31
  const int b  = bh >> 4, h = bh & 15;
  const int t  = threadIdx.x;
  const int q  = t >> 4;
  const int d0 = (t & 15) * 4;
  const int mb = bh * 32 * 16;

  float mv[32];
  float M = -1e30f;
#pragma unroll
  for (int p = 0; p < 32; ++p) {
    mv[p] = mbuf[mb + p * 16 + q];
    M = fmaxf(M, mv[p]);
  }
  float L = 0.f;
  float4 acc = {0.f, 0.f, 0.f, 0.f};
#pragma unroll
  for (int p = 0; p < 32; ++p) {
    const float wp = __expf(mv[p] - M);
    L += lbuf[mb + p * 16 + q] * wp;
    float4 o = *(const float4*)&Obuf[(((size_t)(bh * 32 + p)) * 16 + q) * 64 + d0];
    acc.x += wp * o.x; acc.y += wp * o.y;
    acc.z += wp * o.z; acc.w += wp * o.w;
  }
  const float inv = 1.0f / L;
  uint2 wv;
  wv.x = (u32)f2bf(acc.x * inv) | ((u32)f2bf(acc.y * inv) << 16);
  wv.y = (u32)f2bf(acc.z * inv) | ((u32)f2bf(acc.w * inv) << 16);
  *(uint2*)(out + ((size_t)b * S_LEN + q) * 1024 + h * 64 + d0) = wv;
}

// ---------------------------------------------------------------------------
// Consolidated prep: 6 weight transposes (fp32 -> bf16) + bias concat.
// ---------------------------------------------------------------------------
__global__ __launch_bounds__(256) void prep_all(
    const float* __restrict__ Wq, const float* __restrict__ Wk,
    const float* __restrict__ Wv, const float* __restrict__ Wo,
    const float* __restrict__ W1, const float* __restrict__ W2,
    const float* __restrict__ bq, const float* __restrict__ bk,
    const float* __restrict__ bv,
    u16* __restrict__ WQKVT, u16* __restrict__ WOT,
    u16* __restrict__ W1T, u16* __restrict__ W2T,
    float* __restrict__ BQKV)
{
  const int gb = blockIdx.x;
  const int t = threadIdx.x;
  if (gb >= 3072) {  // concat
    const int i = (gb - 3072) * 256 + t;
    if (i < 1024) BQKV[i] = bq[i];
    else if (i < 2048) BQKV[i] = bk[i - 1024];
    else BQKV[i] = bv[i - 2048];
    return;
  }
  const float* in; u16* outp; int R, Cc, bx, by;
  if (gb < 1024) {
    const int seg = gb >> 8, local = gb & 255;
    bx = local & 15; by = local >> 4; R = 1024; Cc = 1024;
    in   = (seg == 0) ? Wq : (seg == 1) ? Wk : (seg == 2) ? Wv : Wo;
    outp = (seg < 3) ? WQKVT + (size_t)seg * 1024 * 1024 : WOT;
  } else if (gb < 2048) {
    const int local = gb - 1024;
    bx = local & 63; by = local >> 6; R = 1024; Cc = 4096;
    in = W1; outp = W1T;
  } else {
    const int local = gb - 2048;
    bx = local & 15; by = local >> 4; R = 4096; Cc = 1024;
    in = W2; outp = W2T;
  }

  __shared__ u16 tile[64][65];
  const int tr = by * 64, tc = bx * 64;
  const int lr = t >> 2, lc0 = (t & 3) * 16;
  const float* src = in + (size_t)(tr + lr) * Cc + tc + lc0;
  float4 a0 = *(const float4*)(src);
  float4 a1 = *(const float4*)(src + 4);
  float4 a2 = *(const float4*)(src + 8);
  float4 a3 = *(const float4*)(src + 12);
  const float vals[16] = {a0.x, a0.y, a0.z, a0.w, a1.x, a1.y, a1.z, a1.w,
                          a2.x, a2.y, a2.z, a2.w, a3.x, a3.y, a3.z, a3.w};
#pragma unroll
  for (int q = 0; q < 16; ++q) tile[lr][lc0 + q] = f2bf(vals[q]);
  __syncthreads();
  u16* dst = outp + (size_t)(tc + lr) * R + tr + lc0;
  u32 w[8];
#pragma unroll
  for (int q = 0; q < 8; ++q)
    w[q] = (u32)tile[lc0 + 2 * q][lr] | ((u32)tile[lc0 + 2 * q + 1][lr] << 16);
  uint4 s0; s0.x = w[0]; s0.y = w[1]; s0.z = w[2]; s0.w = w[3];
  uint4 s1; s1.x = w[4]; s1.y = w[5]; s1.z = w[6]; s1.w = w[7];
  *(uint4*)dst = s0;
  *(uint4*)(dst + 8) = s1;
}

// ---------------------------------------------------------------------------
// workspace layout (bytes) — ~64 MB (validated rounds 3-13).
// W2 split-K3 partials: W1T (dead after W1), XN (dead after W1),
// WQKVT+WOT @ ws+0 (6+2 MB contiguous, dead after Wo GEMM).
// ---------------------------------------------------------------------------
static const size_t OFF_WQKVT = 0;                                   // bf16 [3072][1024]
static const size_t OFF_WOT   = OFF_WQKVT + (size_t)3072 * 1024 * 2; // bf16 [1024][1024]
static const size_t OFF_W1T   = OFF_WOT   + (size_t)1024 * 1024 * 2; // bf16 [4096][1024]
static const size_t OFF_W2T   = OFF_W1T   + (size_t)4096 * 1024 * 2; // bf16 [1024][4096]
static const size_t OFF_BQKV  = OFF_W2T   + (size_t)1024 * 4096 * 2; // fp32 [3072]
static const size_t OFF_XN    = OFF_BQKV  + 16384;                   // bf16 [4096][1024]
static const size_t OFF_QKV   = OFF_XN    + (size_t)4096 * 1024 * 2; // bf16 [4096][3072]
static const size_t OFF_AO    = OFF_QKV   + (size_t)4096 * 3072 * 2; // bf16 [4096][1024]
static const size_t OFF_H     = OFF_QKV;  // bf16 [4096][4096], aliases QKV+AO

extern "C" void kernel_launch(void* const* d_in, const int* in_sizes, int n_in,
                              void* d_out, int out_size, void* d_ws, size_t ws_size,
                              hipStream_t stream)
{
  const float* x   = (const float*)d_in[0];
  const float* Wq  = (const float*)d_in[1];
  const float* bq  = (const float*)d_in[2];
  const float* Wk  = (const float*)d_in[3];
  const float* bk  = (const float*)d_in[4];
  const float* Wv  = (const float*)d_in[5];
  const float* bv  = (const float*)d_in[6];
  const float* Wo  = (const float*)d_in[7];
  const float* bo  = (const float*)d_in[8];
  const float* g1  = (const float*)d_in[9];
  const float* be1 = (const float*)d_in[10];
  const float* W1  = (const float*)d_in[11];
  const float* b1  = (const float*)d_in[12];
  const float* W2  = (const float*)d_in[13];
  const float* b2  = (const float*)d_in[14];
  const float* g2  = (const float*)d_in[15];
  const float* be2 = (const float*)d_in[16];
  float* outf = (float*)d_out;
  char* ws = (char*)d_ws;

  u16*   WQKVT = (u16*)(ws + OFF_WQKVT);
  u16*   WOT   = (u16*)(ws + OFF_WOT);
  u16*   W1T   = (u16*)(ws + OFF_W1T);
  u16*   W2T   = (u16*)(ws + OFF_W2T);
  float* BQKV  = (float*)(ws + OFF_BQKV);
  u16*   XN    = (u16*)(ws + OFF_XN);
  u16*   QKV   = (u16*)(ws + OFF_QKV);
  u16*   AO    = (u16*)(ws + OFF_AO);
  u16*   Hbuf  = (u16*)(ws + OFF_H);
  float* X1    = outf;  // fp32 residual stream #2 lives in d_out
  // Wo split-K4 partials (QKV region x3 + XN)
  u16* PWo0 = (u16*)(ws + OFF_QKV);
  u16* PWo1 = PWo0 + (size_t)4096 * 1024;
  u16* PWo2 = PWo1 + (size_t)4096 * 1024;
  u16* PWo3 = (u16*)(ws + OFF_XN);
  // W2 split-K3 partials
  u16* PW20 = (u16*)(ws + OFF_W1T);
  u16* PW21 = (u16*)(ws + OFF_XN);
  u16* PW22 = (u16*)(ws + 0);     // WQKVT+WOT region (8 MB, dead after Wo)
  float* GO = (float*)(ws + OFF_XN);
  float* GM = GO + (size_t)32 * 32 * 16 * 64;
  float* GL = GM + 32 * 32 * 16;

  const dim3 blk(256);
  const dim3 blk512(512);
  prep_all<<<dim3(3084), blk, 0, stream>>>(Wq, Wk, Wv, Wo, W1, W2, bq, bk, bv,
                                           WQKVT, WOT, W1T, W2T, BQKV);

  // attention sublayer
  ln_kernel<<<dim3(ROWS), blk, 0, stream>>>(x, g1, be1, XN);
  gemm256<0, 1024><<<dim3(12, 16, 1), blk512, 0, stream>>>(
      XN, WQKVT, BQKV, QKV, QKV, QKV, QKV, 3072, 1024, 1024);
  attn_band<<<dim3(32, 32), blk, 0, stream>>>(QKV, AO);
  attn_gpart<<<dim3(8, 32), blk, 0, stream>>>(QKV, GO, GM, GL);
  attn_gcombine<<<dim3(32), blk, 0, stream>>>(GO, GM, GL, AO);
  gemm256<2, 1024><<<dim3(4, 16, 4), blk512, 0, stream>>>(
      AO, WOT, nullptr, PWo0, PWo1, PWo2, PWo3, 1024, 256, 1024);
  // fused: X1 = sum(partials)+bo+x ; XN = LN2(X1)
  reduce4_ln<<<dim3(ROWS), blk, 0, stream>>>(PWo0, PWo1, PWo2, PWo3,
                                             bo, x, g2, be2, X1, XN);

  // FFN sublayer
  gemm256<1, 1024><<<dim3(16, 16, 1), blk512, 0, stream>>>(
      XN, W1T, b1, Hbuf, Hbuf, Hbuf, Hbuf, 4096, 1024, 1024);
  gemm256<2, 4096><<<dim3(4, 16, 3), blk512, 0, stream>>>(
      Hbuf, W2T, nullptr, PW20, PW21, PW22, PW22, 1024, 1536, 4096);
  reduce3<<<dim3(2048), blk, 0, stream>>>(PW20, PW21, PW22, b2, X1, outf);
}

// Round 8
// 334.530 us; speedup vs baseline: 1.1146x; 1.0316x over previous
//
#include <hip/hip_runtime.h>
#include <stdint.h>

// ---------------------------------------------------------------------------
// EncoderBlock: pre-norm transformer block, MI355X (gfx950).
// External dtype: FP32. Internal: bf16 MFMA, fp32 accum, fp32 residual.
// B=2 S=2048 D=1024 H=16 DK=64 DFF=4096 WINDOW=128 GLOBAL=16
// Round 15: attn_band rewritten with KVBLK=64 (was 32): 6 chunks/block
// (was 11), 16 MFMA/wave per barrier pair (was 8), V-transpose staged as
// paired-key u32 writes (conflict-free, half the LDS stores). GEMM engine
// and graph structure identical to round 14 (345.1us best).
// ---------------------------------------------------------------------------

typedef unsigned short u16;
typedef unsigned int   u32;
typedef __attribute__((ext_vector_type(8))) short  short8;  // 8 bf16 (4 VGPRs)
typedef __attribute__((ext_vector_type(4))) float  f32x4;

#define S_LEN   2048
#define D_MODEL 1024
#define ROWS    4096   // B*S

__device__ __forceinline__ float bf2f(u16 u) {
  union { u32 i; float f; } v; v.i = ((u32)u) << 16; return v.f;
}
__device__ __forceinline__ float bflo(u32 u) {
  union { u32 i; float f; } v; v.i = u << 16; return v.f;
}
__device__ __forceinline__ float bfhi(u32 u) {
  union { u32 i; float f; } v; v.i = u & 0xffff0000u; return v.f;
}
__device__ __forceinline__ u16 f2bf(float f) {
  union { float f; u32 i; } v; v.f = f;
  u32 r = v.i + 0x7fffu + ((v.i >> 16) & 1u);
  return (u16)(r >> 16);
}

// Direct global->LDS copy, 16B/lane (m97). Lands at wave base + lane*16.
__device__ __forceinline__ void gld_lds16(const u16* g, u16* l) {
  __attribute__((address_space(3))) u32* lp =
      reinterpret_cast<__attribute__((address_space(3))) u32*>(
          reinterpret_cast<uintptr_t>(l));
  const __attribute__((address_space(1))) u32* gp =
      reinterpret_cast<const __attribute__((address_space(1))) u32*>(
          reinterpret_cast<uintptr_t>(g));
  __builtin_amdgcn_global_load_lds(gp, lp, 16, 0, 0);
}

// ---------------------------------------------------------------------------
// gemm256 v3 (round-10, verified): 256x256 tile, BK=64, 512 threads
// (8 waves, 2M x 4N). Derived-waits 8-phase schedule + sched_barrier(0)
// pin after each wait. LDS: A/B each [buf 2][khalf 2][256 rows x 32 elems],
// k-chunk rotate swizzle (bank-conflict free, SQ_LDS_BANK_CONFLICT=0).
// K-slice runtime: slice kz covers [kz*kc0, min((kz+1)*kc0, Ktot)).
// EPI: 0 = bias, 1 = bias+gelu, 2 = raw bf16 partial (split-K via grid.z).
// ---------------------------------------------------------------------------

#define GBAR  asm volatile("s_barrier" ::: "memory")
#define LGKM(n) asm volatile("s_waitcnt lgkmcnt(" #n ")" ::: "memory")
#define VM(n)   asm volatile("s_waitcnt vmcnt(" #n ")" ::: "memory")
#define SB0   __builtin_amdgcn_sched_barrier(0)

#define STAGE_A(buf, t, hm) do {                                              \
    gld_lds16(pA##hm + (size_t)(t) * 64,      &Ald[buf][0][(hm)*4096 + ldst]);\
    gld_lds16(pA##hm + (size_t)(t) * 64 + 32, &Ald[buf][1][(hm)*4096 + ldst]);\
  } while (0)

#define STAGE_B(buf, t, hm) do {                                              \
    gld_lds16(pB##hm + (size_t)(t) * 64,      &Bld[buf][0][(hm)*4096 + ldst]);\
    gld_lds16(pB##hm + (size_t)(t) * 64 + 32, &Bld[buf][1][(hm)*4096 + ldst]);\
  } while (0)

#define READ_B(buf) do {                                                      \
    _Pragma("unroll") for (int nj = 0; nj < 4; ++nj) {                        \
      bfv[nj][0] = *(const short8*)&Bld[buf][0][brow + nj * 512];             \
      bfv[nj][1] = *(const short8*)&Bld[buf][1][brow + nj * 512]; }           \
  } while (0)

// READ_A(buf,q): prefetch quadrant q fragments into af[q&1] (ping-pong).
#define READ_A(buf, q) do {                                                   \
    af[(q)&1][0][0] = *(const short8*)&Ald[buf][0][arow + (2*(q)) * 512];     \
    af[(q)&1][0][1] = *(const short8*)&Ald[buf][1][arow + (2*(q)) * 512];     \
    af[(q)&1][1][0] = *(const short8*)&Ald[buf][0][arow + (2*(q)+1) * 512];   \
    af[(q)&1][1][1] = *(const short8*)&Ald[buf][1][arow + (2*(q)+1) * 512];   \
  } while (0)

#define MFMA_Q(q) do {                                                        \
    __builtin_amdgcn_s_setprio(1);                                            \
    _Pragma("unroll") for (int dm = 0; dm < 2; ++dm)                          \
    _Pragma("unroll") for (int kk = 0; kk < 2; ++kk)                          \
    _Pragma("unroll") for (int nj = 0; nj < 4; ++nj)                          \
      acc[2*(q)+dm][nj] = __builtin_amdgcn_mfma_f32_16x16x32_bf16(            \
          af[(q)&1][dm][kk], bfv[nj][kk], acc[2*(q)+dm][nj], 0, 0, 0);        \
    __builtin_amdgcn_s_setprio(0);                                            \
  } while (0)

template <int EPI, int LDK>
__global__ __launch_bounds__(512) void gemm256(
    const u16* __restrict__ A, const u16* __restrict__ Bt,
    const float* __restrict__ bias, u16* __restrict__ C0,
    u16* __restrict__ C1, u16* __restrict__ C2, u16* __restrict__ C3,
    int N, int kc0, int Ktot)
{
  __shared__ __attribute__((aligned(16))) u16 Ald[2][2][256 * 32];
  __shared__ __attribute__((aligned(16))) u16 Bld[2][2][256 * 32];

  const int tid  = threadIdx.x;
  const int w    = tid >> 6;
  const int lane = tid & 63;
  const int wm   = w >> 2;       // 0..1  (M half)
  const int wn   = w & 3;        // 0..3  (N quarter)
  const int lm   = lane & 15;
  const int kq   = lane >> 4;
  const int bm   = blockIdx.y * 256;
  const int bn   = blockIdx.x * 256;
  const int kz   = blockIdx.z;

  const int koff = kz * kc0;
  const int kc   = min(kc0, Ktot - koff);
  const int P    = kc >> 7;   // pair count (2 K-tiles of 64); kc % 128 == 0

  const u16* Ak = A  + (size_t)koff;
  const u16* Bk = Bt + (size_t)koff;
  u16* C = (kz == 0) ? C0 : (kz == 1) ? C1 : (kz == 2) ? C2 : C3;

  // read-side swizzled chunk slot (row bases are multiples of 16).
  const int rslot = ((kq + (lm >> 1)) & 3) * 8;
  const int arow  = (wm * 128 + lm) * 32 + rslot;   // + mi*512
  const int brow  = (wn * 64  + lm) * 32 + rslot;   // + nj*512

  // stage-side: lane covers row (lane>>2), LDS chunk slot (lane&3).
  const int gcoff = (((lane & 3) - (lane >> 3)) & 3) * 8;
  const int srow  = w * 16 + (lane >> 2);           // row within 128-half
  const int ldst  = w * 512;                        // wave LDS base (u16)

  const u16* pA0 = Ak + (size_t)(bm + srow) * LDK + gcoff;
  const u16* pA1 = pA0 + (size_t)128 * LDK;
  const u16* pB0 = Bk + (size_t)(bn + srow) * LDK + gcoff;
  const u16* pB1 = pB0 + (size_t)128 * LDK;

  f32x4 acc[8][4];
#pragma unroll
  for (int i = 0; i < 8; ++i)
#pragma unroll
    for (int j = 0; j < 4; ++j) acc[i][j] = (f32x4){0.f, 0.f, 0.f, 0.f};

  short8 af[2][2][2];   // [parity][dm][khalf]
  short8 bfv[4][2];

  // prologue: tile0 (A+B) + tile1.B staged; vmcnt(4) keeps t1.B in flight.
  STAGE_B(0, 0, 0); STAGE_B(0, 0, 1);
  STAGE_A(0, 0, 0); STAGE_A(0, 0, 1);
  STAGE_B(1, 1, 0); STAGE_B(1, 1, 1);
  VM(4);
  GBAR;
  READ_A(0, 0);   // prefetch q0 for first MFMA

#pragma unroll 1
  for (int i = 0; i < P - 1; ++i) {
    const int t1 = 2 * i + 1, t2 = 2 * i + 2, t3 = 2 * i + 3;
    GBAR; STAGE_A(1, t1, 0); READ_B(0); READ_A(0, 1); LGKM(4); SB0; MFMA_Q(0);
    GBAR; STAGE_A(1, t1, 1); READ_A(0, 2);            LGKM(4); SB0; MFMA_Q(1);
    GBAR; STAGE_B(0, t2, 0); READ_A(0, 3);            LGKM(4); SB0; MFMA_Q(2);
    VM(2);
    GBAR; STAGE_B(0, t2, 1); READ_A(1, 0);            LGKM(4); SB0; MFMA_Q(3);
    GBAR; STAGE_A(0, t2, 0); READ_B(1); READ_A(1, 1); LGKM(4); SB0; MFMA_Q(0);
    GBAR; STAGE_A(0, t2, 1); READ_A(1, 2);            LGKM(4); SB0; MFMA_Q(1);
    GBAR; STAGE_B(1, t3, 0); READ_A(1, 3);            LGKM(4); SB0; MFMA_Q(2);
    VM(2);
    GBAR; STAGE_B(1, t3, 1); READ_A(0, 0);            LGKM(4); SB0; MFMA_Q(3);
  }
  {  // final pair: tile (2P-2) in buf0, (2P-1) in buf1 (B already staged).
    const int t1 = 2 * P - 1;
    GBAR; STAGE_A(1, t1, 0); READ_B(0); READ_A(0, 1); LGKM(4); SB0; MFMA_Q(0);
    GBAR; STAGE_A(1, t1, 1); READ_A(0, 2);            LGKM(4); SB0; MFMA_Q(1);
    GBAR;                    READ_A(0, 3);            LGKM(4); SB0; MFMA_Q(2);
    VM(0);
    GBAR;                    READ_A(1, 0);            LGKM(4); SB0; MFMA_Q(3);
    GBAR;                    READ_B(1); READ_A(1, 1); LGKM(4); SB0; MFMA_Q(0);
    GBAR;                    READ_A(1, 2);            LGKM(4); SB0; MFMA_Q(1);
    GBAR;                    READ_A(1, 3);            LGKM(4); SB0; MFMA_Q(2);
    LGKM(0); SB0; MFMA_Q(3);
  }

  const int r0 = kq * 4;
#pragma unroll
  for (int mi = 0; mi < 8; ++mi) {
#pragma unroll
    for (int r = 0; r < 4; ++r) {
      const int grow = bm + wm * 128 + mi * 16 + r0 + r;
#pragma unroll
      for (int nj = 0; nj < 4; ++nj) {
        const int gcol = bn + wn * 64 + nj * 16 + lm;
        float v = acc[mi][nj][r];
        if (EPI < 2) v += bias[gcol];
        if (EPI == 1) v = 0.5f * v * (1.0f + erff(v * 0.70710678118654752f));
        C[(size_t)grow * N + gcol] = f2bf(v);
      }
    }
  }
}

// out[idx] = P0+P1+P2 + bias[col] + res[idx]   (N fixed = 1024)
__global__ __launch_bounds__(256) void reduce3(
    const u16* __restrict__ P0, const u16* __restrict__ P1,
    const u16* __restrict__ P2,
    const float* __restrict__ bias, const float* res, float* out)
{
  const size_t base = ((size_t)blockIdx.x * 256 + threadIdx.x) * 8;
  const int col = (int)(base & 1023);
  uint4 p0 = *(const uint4*)(P0 + base);
  uint4 p1 = *(const uint4*)(P1 + base);
  uint4 p2 = *(const uint4*)(P2 + base);
  float4 b0 = *(const float4*)(bias + col);
  float4 b1 = *(const float4*)(bias + col + 4);
  float4 r0 = *(const float4*)(res + base);
  float4 r1 = *(const float4*)(res + base + 4);
  float4 o0, o1;
  o0.x = bflo(p0.x) + bflo(p1.x) + bflo(p2.x) + b0.x + r0.x;
  o0.y = bfhi(p0.x) + bfhi(p1.x) + bfhi(p2.x) + b0.y + r0.y;
  o0.z = bflo(p0.y) + bflo(p1.y) + bflo(p2.y) + b0.z + r0.z;
  o0.w = bfhi(p0.y) + bfhi(p1.y) + bfhi(p2.y) + b0.w + r0.w;
  o1.x = bflo(p0.z) + bflo(p1.z) + bflo(p2.z) + b1.x + r1.x;
  o1.y = bfhi(p0.z) + bfhi(p1.z) + bfhi(p2.z) + b1.y + r1.y;
  o1.z = bflo(p0.w) + bflo(p1.w) + bflo(p2.w) + b1.z + r1.z;
  o1.w = bfhi(p0.w) + bfhi(p1.w) + bfhi(p2.w) + b1.w + r1.w;
  *(float4*)(out + base) = o0;
  *(float4*)(out + base + 4) = o1;
}

// ---------------------------------------------------------------------------
// Fused Wo-boundary: X1 = P0+P1+P2+P3 + bo + x;  XN = LN(X1, g2, be2).
// ---------------------------------------------------------------------------
__global__ __launch_bounds__(256) void reduce4_ln(
    const u16* __restrict__ P0, const u16* __restrict__ P1,
    const u16* __restrict__ P2, const u16* __restrict__ P3,
    const float* __restrict__ bias, const float* __restrict__ res,
    const float* __restrict__ g, const float* __restrict__ bp,
    float* __restrict__ X1, u16* __restrict__ XN)
{
  const int row = blockIdx.x;
  const int t = threadIdx.x;
  const size_t base = (size_t)row * D_MODEL + t * 4;
  const int col = t * 4;
  uint2 a0 = *(const uint2*)(P0 + base);
  uint2 a1 = *(const uint2*)(P1 + base);
  uint2 a2 = *(const uint2*)(P2 + base);
  uint2 a3 = *(const uint2*)(P3 + base);
  float4 bb = *(const float4*)(bias + col);
  float4 rr = *(const float4*)(res + base);
  float4 y;
  y.x = bflo(a0.x) + bflo(a1.x) + bflo(a2.x) + bflo(a3.x) + bb.x + rr.x;
  y.y = bfhi(a0.x) + bfhi(a1.x) + bfhi(a2.x) + bfhi(a3.x) + bb.y + rr.y;
  y.z = bflo(a0.y) + bflo(a1.y) + bflo(a2.y) + bflo(a3.y) + bb.z + rr.z;
  y.w = bfhi(a0.y) + bfhi(a1.y) + bfhi(a2.y) + bfhi(a3.y) + bb.w + rr.w;
  *(float4*)(X1 + base) = y;

  float s  = y.x + y.y + y.z + y.w;
  float ss = y.x * y.x + y.y * y.y + y.z * y.z + y.w * y.w;
#pragma unroll
  for (int off = 32; off > 0; off >>= 1) {
    s  += __shfl_down(s, off);
    ss += __shfl_down(ss, off);
  }
  __shared__ float sm[4], ssm[4], stat[2];
  if ((t & 63) == 0) { sm[t >> 6] = s; ssm[t >> 6] = ss; }
  __syncthreads();
  if (t == 0) {
    float S = sm[0] + sm[1] + sm[2] + sm[3];
    float SS = ssm[0] + ssm[1] + ssm[2] + ssm[3];
    float mu = S * (1.0f / 1024.0f);
    float var = SS * (1.0f / 1024.0f) - mu * mu;
    stat[0] = mu;
    stat[1] = rsqrtf(fmaxf(var, 0.0f) + 1e-5f);
  }
  __syncthreads();
  const float mu = stat[0], rstd = stat[1];
  float4 gg = *(const float4*)(g + col);
  float4 be = *(const float4*)(bp + col);
  u16 o0 = f2bf((y.x - mu) * rstd * gg.x + be.x);
  u16 o1 = f2bf((y.y - mu) * rstd * gg.y + be.y);
  u16 o2 = f2bf((y.z - mu) * rstd * gg.z + be.z);
  u16 o3 = f2bf((y.w - mu) * rstd * gg.w + be.w);
  uint2 wv;
  wv.x = (u32)o0 | ((u32)o1 << 16);
  wv.y = (u32)o2 | ((u32)o3 << 16);
  *(uint2*)(XN + base) = wv;
}

// ---------------------------------------------------------------------------
// LayerNorm: fp32 in, bf16 out. One block per row (D=1024).
// ---------------------------------------------------------------------------
__global__ __launch_bounds__(256) void ln_kernel(
    const float* __restrict__ x, const float* __restrict__ g,
    const float* __restrict__ b, u16* __restrict__ o)
{
  const int row = blockIdx.x;
  const int t = threadIdx.x;
  float4 v = *(const float4*)(x + (size_t)row * D_MODEL + t * 4);
  float s  = v.x + v.y + v.z + v.w;
  float ss = v.x * v.x + v.y * v.y + v.z * v.z + v.w * v.w;
#pragma unroll
  for (int off = 32; off > 0; off >>= 1) {
    s  += __shfl_down(s, off);
    ss += __shfl_down(ss, off);
  }
  __shared__ float sm[4], ssm[4], stat[2];
  if ((t & 63) == 0) { sm[t >> 6] = s; ssm[t >> 6] = ss; }
  __syncthreads();
  if (t == 0) {
    float S = sm[0] + sm[1] + sm[2] + sm[3];
    float SS = ssm[0] + ssm[1] + ssm[2] + ssm[3];
    float mu = S * (1.0f / 1024.0f);
    float var = SS * (1.0f / 1024.0f) - mu * mu;
    stat[0] = mu;
    stat[1] = rsqrtf(fmaxf(var, 0.0f) + 1e-5f);
  }
  __syncthreads();
  const float mu = stat[0], rstd = stat[1];
  float4 gg = *(const float4*)(g + t * 4);
  float4 bb = *(const float4*)(b + t * 4);
  u16 o0 = f2bf((v.x - mu) * rstd * gg.x + bb.x);
  u16 o1 = f2bf((v.y - mu) * rstd * gg.y + bb.y);
  u16 o2 = f2bf((v.z - mu) * rstd * gg.z + bb.z);
  u16 o3 = f2bf((v.w - mu) * rstd * gg.w + bb.w);
  uint2 w;
  w.x = (u32)o0 | ((u32)o1 << 16);
  w.y = (u32)o2 | ((u32)o3 << 16);
  *(uint2*)(o + (size_t)row * D_MODEL + t * 4) = w;
}

// ---------------------------------------------------------------------------
// Banded attention, KVBLK=64 flash style (round 15).
// Per block: 64 Q rows (4 waves x 16), chunks of 64 keys.
// Chunk 0 = keys [0,64) (covers global j<16 + near band);
// banded chunks from lo = max(64, i0-128) to hi = min(S, i0+192).
// All chunk bounds are multiples of 64. Mask: j<16 || |i-j|<=128.
// K staged row-major [64][72]; V staged TRANSPOSED d-major [64][68]
// via paired-key u32 writes (32 lanes -> 32 consecutive dwords,
// conflict-free). 16 MFMA/wave per chunk (8 QK + 8 PV).
// ---------------------------------------------------------------------------
__global__ __launch_bounds__(256) void attn_band(
    const u16* __restrict__ qkv, u16* __restrict__ out)
{
  const int t    = threadIdx.x;
  const int w    = t >> 6;
  const int lane = t & 63;
  const int m    = lane & 15;
  const int quad = lane >> 4;
  const int bh   = blockIdx.y;
  const int b    = bh >> 4, h = bh & 15;
  const int i0   = blockIdx.x * 64;
  const size_t bb = (size_t)b * S_LEN;

  __shared__ __attribute__((aligned(16))) u16 Ks[64 * 72];
  __shared__ __attribute__((aligned(16))) u16 Vt[64 * 68];
  __shared__ __attribute__((aligned(16))) u16 Ps[4][16 * 72];

  const u16* qrow = qkv + (bb + i0 + 16 * w + m) * 3072 + h * 64;
  const short8 aq0 = *(const short8*)(qrow + quad * 8);
  const short8 aq1 = *(const short8*)(qrow + 32 + quad * 8);

  f32x4 Ov[4];
#pragma unroll
  for (int td = 0; td < 4; ++td) Ov[td] = (f32x4){0.f, 0.f, 0.f, 0.f};
  float mP[4] = {-1e30f, -1e30f, -1e30f, -1e30f};
  float lS[4] = {0.f, 0.f, 0.f, 0.f};

  const int iB = i0 + 16 * w + quad * 4;

  const int lo = max(64, i0 - 128);
  const int hi = min(S_LEN, i0 + 192);
  const int nChunks = 1 + (hi - lo) / 64;

  // K staging: thread t covers row t>>2 (0..63), d-col (t&3)*16 (2x uint4).
  const int skr = t >> 2;
  const int skc = (t & 3) * 16;
  // V staging: thread t covers key-pair (t&31)*2, d-base (t>>5)*8.
  const int vkp = (t & 31) * 2;
  const int vd0 = (t >> 5) * 8;

  for (int c = 0; c < nChunks; ++c) {
    const int j0 = (c == 0) ? 0 : lo + (c - 1) * 64;
    __syncthreads();
    {
      const u16* ksrc = qkv + (bb + j0 + skr) * 3072 + 1024 + h * 64 + skc;
      uint4 k0 = *(const uint4*)ksrc;
      uint4 k1 = *(const uint4*)(ksrc + 8);
      *(uint4*)&Ks[skr * 72 + skc]     = k0;
      *(uint4*)&Ks[skr * 72 + skc + 8] = k1;
      const u16* vsrc = qkv + (bb + j0 + vkp) * 3072 + 2048 + h * 64 + vd0;
      uint4 v0 = *(const uint4*)vsrc;           // key vkp,   d vd0..+8
      uint4 v1 = *(const uint4*)(vsrc + 3072);  // key vkp+1, d vd0..+8
      const u16 va[8] = {
        (u16)(v0.x & 0xffffu), (u16)(v0.x >> 16),
        (u16)(v0.y & 0xffffu), (u16)(v0.y >> 16),
        (u16)(v0.z & 0xffffu), (u16)(v0.z >> 16),
        (u16)(v0.w & 0xffffu), (u16)(v0.w >> 16)};
      const u16 vb[8] = {
        (u16)(v1.x & 0xffffu), (u16)(v1.x >> 16),
        (u16)(v1.y & 0xffffu), (u16)(v1.y >> 16),
        (u16)(v1.z & 0xffffu), (u16)(v1.z >> 16),
        (u16)(v1.w & 0xffffu), (u16)(v1.w >> 16)};
#pragma unroll
      for (int j = 0; j < 8; ++j)
        *(u32*)&Vt[(vd0 + j) * 68 + vkp] = (u32)va[j] | ((u32)vb[j] << 16);
    }
    __syncthreads();

    // QK^T: 4 key-groups of 16; score tile g: rows iB.., cols j0+16g+m.
    f32x4 s[4];
#pragma unroll
    for (int g = 0; g < 4; ++g) {
      const short8 bg0 = *(const short8*)&Ks[(16 * g + m) * 72 + quad * 8];
      const short8 bg1 = *(const short8*)&Ks[(16 * g + m) * 72 + 32 + quad * 8];
      f32x4 sg = (f32x4){0.f, 0.f, 0.f, 0.f};
      sg = __builtin_amdgcn_mfma_f32_16x16x32_bf16(aq0, bg0, sg, 0, 0, 0);
      sg = __builtin_amdgcn_mfma_f32_16x16x32_bf16(aq1, bg1, sg, 0, 0, 0);
      s[g] = sg;
    }

#pragma unroll
    for (int g = 0; g < 4; ++g) {
      const int jG = j0 + 16 * g + m;
#pragma unroll
      for (int r = 0; r < 4; ++r) {
        const int d = iB + r - jG;
        s[g][r] = ((jG < 16) || (d >= -128 && d <= 128)) ? s[g][r] * 0.125f
                                                         : -1e30f;
      }
    }

    float al[4];
#pragma unroll
    for (int r = 0; r < 4; ++r) {
      float mx = fmaxf(fmaxf(s[0][r], s[1][r]), fmaxf(s[2][r], s[3][r]));
      mx = fmaxf(mx, __shfl_xor(mx, 1, 16));
      mx = fmaxf(mx, __shfl_xor(mx, 2, 16));
      mx = fmaxf(mx, __shfl_xor(mx, 4, 16));
      mx = fmaxf(mx, __shfl_xor(mx, 8, 16));
      const float mn = fmaxf(mP[r], mx);
      al[r] = __expf(mP[r] - mn);
      mP[r] = mn;
      const float p0 = __expf(s[0][r] - mn);
      const float p1 = __expf(s[1][r] - mn);
      const float p2 = __expf(s[2][r] - mn);
      const float p3 = __expf(s[3][r] - mn);
      float ps = (p0 + p1) + (p2 + p3);
      ps += __shfl_xor(ps, 1, 16);
      ps += __shfl_xor(ps, 2, 16);
      ps += __shfl_xor(ps, 4, 16);
      ps += __shfl_xor(ps, 8, 16);
      lS[r] = lS[r] * al[r] + ps;
      const int pr = (quad * 4 + r) * 72 + m;
      Ps[w][pr]      = f2bf(p0);
      Ps[w][pr + 16] = f2bf(p1);
      Ps[w][pr + 32] = f2bf(p2);
      Ps[w][pr + 48] = f2bf(p3);
    }
#pragma unroll
    for (int td = 0; td < 4; ++td)
#pragma unroll
      for (int r = 0; r < 4; ++r) Ov[td][r] *= al[r];

    // PV: A = P (rows=q, k=key 0..63 in 2 frags), B = V^T (d-major Vt).
    const short8 pa0 = *(const short8*)&Ps[w][m * 72 + quad * 8];
    const short8 pa1 = *(const short8*)&Ps[w][m * 72 + 32 + quad * 8];
#pragma unroll
    for (int td = 0; td < 4; ++td) {
      const short8 bv0 = *(const short8*)&Vt[(td * 16 + m) * 68 + quad * 8];
      const short8 bv1 = *(const short8*)&Vt[(td * 16 + m) * 68 + 32 + quad * 8];
      Ov[td] = __builtin_amdgcn_mfma_f32_16x16x32_bf16(pa0, bv0, Ov[td], 0, 0, 0);
      Ov[td] = __builtin_amdgcn_mfma_f32_16x16x32_bf16(pa1, bv1, Ov[td], 0, 0, 0);
    }
  }

  if (i0 + 16 * w >= 16) {
    float inv[4];
#pragma unroll
    for (int r = 0; r < 4; ++r) inv[r] = 1.0f / lS[r];
#pragma unroll
    for (int td = 0; td < 4; ++td)
#pragma unroll
      for (int r = 0; r < 4; ++r)
        out[(bb + iB + r) * 1024 + h * 64 + td * 16 + m] =
            f2bf(Ov[td][r] * inv[r]);
  }
}

// ---------------------------------------------------------------------------
// Global rows (i<16): MFMA split-K partials + combine (round-7 verified).
// ---------------------------------------------------------------------------
__global__ __launch_bounds__(256) void attn_gpart(
    const u16* __restrict__ qkv, float* __restrict__ Obuf,
    float* __restrict__ mbuf, float* __restrict__ lbuf)
{
  const int t    = threadIdx.x;
  const int w    = t >> 6;
  const int lane = t & 63;
  const int m    = lane & 15;
  const int quad = lane >> 4;
  const int kb   = blockIdx.x;   // 0..7
  const int bh   = blockIdx.y;   // 0..31
  const int b    = bh >> 4, h = bh & 15;
  const size_t bb = (size_t)b * S_LEN;

  __shared__ __attribute__((aligned(16))) u16 Ks[4][32 * 72];
  __shared__ __attribute__((aligned(16))) u16 Vt[4][64 * 40];
  __shared__ __attribute__((aligned(16))) u16 Ps[4][16 * 40];

  const u16* qrow = qkv + (bb + m) * 3072 + h * 64;
  const short8 aq0 = *(const short8*)(qrow + quad * 8);
  const short8 aq1 = *(const short8*)(qrow + 32 + quad * 8);

  f32x4 Ov[4];
#pragma unroll
  for (int td = 0; td < 4; ++td) Ov[td] = (f32x4){0.f, 0.f, 0.f, 0.f};
  float mP[4] = {-1e30f, -1e30f, -1e30f, -1e30f};
  float lS[4] = {0.f, 0.f, 0.f, 0.f};

  const int srow = lane >> 1;
  const int sd   = (lane & 1) * 32;

  for (int c = 0; c < 2; ++c) {
    const int j0 = kb * 256 + w * 64 + c * 32;
    {
      const u16* src = qkv + (bb + j0 + srow) * 3072 + 1024 + h * 64 + sd;
      uint4 k0 = *(const uint4*)(src);
      uint4 k1 = *(const uint4*)(src + 8);
      uint4 k2 = *(const uint4*)(src + 16);
      uint4 k3 = *(const uint4*)(src + 24);
      *(uint4*)&Ks[w][srow * 72 + sd]      = k0;
      *(uint4*)&Ks[w][srow * 72 + sd + 8]  = k1;
      *(uint4*)&Ks[w][srow * 72 + sd + 16] = k2;
      *(uint4*)&Ks[w][srow * 72 + sd + 24] = k3;
#pragma unroll
      for (int q4 = 0; q4 < 4; ++q4) {
        uint4 vv = *(const uint4*)(src + 1024 + q4 * 8);
        const u16 vs[8] = {
          (u16)(vv.x & 0xffffu), (u16)(vv.x >> 16),
          (u16)(vv.y & 0xffffu), (u16)(vv.y >> 16),
          (u16)(vv.z & 0xffffu), (u16)(vv.z >> 16),
          (u16)(vv.w & 0xffffu), (u16)(vv.w >> 16)};
#pragma unroll
        for (int i = 0; i < 8; ++i)
          Vt[w][(sd + q4 * 8 + i) * 40 + srow] = vs[i];
      }
    }

    const short8 b00 = *(const short8*)&Ks[w][m * 72 + quad * 8];
    const short8 b01 = *(const short8*)&Ks[w][m * 72 + 32 + quad * 8];
    const short8 b10 = *(const short8*)&Ks[w][(16 + m) * 72 + quad * 8];
    const short8 b11 = *(const short8*)&Ks[w][(16 + m) * 72 + 32 + quad * 8];
    f32x4 s0 = (f32x4){0.f, 0.f, 0.f, 0.f};
    f32x4 s1 = (f32x4){0.f, 0.f, 0.f, 0.f};
    s0 = __builtin_amdgcn_mfma_f32_16x16x32_bf16(aq0, b00, s0, 0, 0, 0);
    s0 = __builtin_amdgcn_mfma_f32_16x16x32_bf16(aq1, b01, s0, 0, 0, 0);
    s1 = __builtin_amdgcn_mfma_f32_16x16x32_bf16(aq0, b10, s1, 0, 0, 0);
    s1 = __builtin_amdgcn_mfma_f32_16x16x32_bf16(aq1, b11, s1, 0, 0, 0);

    float al[4];
#pragma unroll
    for (int r = 0; r < 4; ++r) {
      const float v0 = s0[r] * 0.125f, v1 = s1[r] * 0.125f;
      float mx = fmaxf(v0, v1);
      mx = fmaxf(mx, __shfl_xor(mx, 1, 16));
      mx = fmaxf(mx, __shfl_xor(mx, 2, 16));
      mx = fmaxf(mx, __shfl_xor(mx, 4, 16));
      mx = fmaxf(mx, __shfl_xor(mx, 8, 16));
      const float mn = fmaxf(mP[r], mx);
      al[r] = __expf(mP[r] - mn);
      mP[r] = mn;
      const float p0 = __expf(v0 - mn);
      const float p1 = __expf(v1 - mn);
      float ps = p0 + p1;
      ps += __shfl_xor(ps, 1, 16);
      ps += __shfl_xor(ps, 2, 16);
      ps += __shfl_xor(ps, 4, 16);
      ps += __shfl_xor(ps, 8, 16);
      lS[r] = lS[r] * al[r] + ps;
      Ps[w][(quad * 4 + r) * 40 + m]      = f2bf(p0);
      Ps[w][(quad * 4 + r) * 40 + 16 + m] = f2bf(p1);
    }
#pragma unroll
    for (int td = 0; td < 4; ++td)
#pragma unroll
      for (int r = 0; r < 4; ++r) Ov[td][r] *= al[r];

    const short8 pa = *(const short8*)&Ps[w][m * 40 + quad * 8];
#pragma unroll
    for (int td = 0; td < 4; ++td) {
      const short8 bv = *(const short8*)&Vt[w][(td * 16 + m) * 40 + quad * 8];
      Ov[td] = __builtin_amdgcn_mfma_f32_16x16x32_bf16(pa, bv, Ov[td], 0, 0, 0);
    }
  }

  const int p = kb * 4 + w;
  const size_t ob = ((size_t)(bh * 32 + p)) * 16 * 64;
#pragma unroll
  for (int td = 0; td < 4; ++td)
#pragma unroll
    for (int r = 0; r < 4; ++r)
      Obuf[ob + (size_t)(quad * 4 + r) * 64 + td * 16 + m] = Ov[td][r];
  if (m == 0) {
    const int mb = (bh * 32 + p) * 16;
#pragma unroll
    for (int r = 0; r < 4; ++r) {
      mbuf[mb + quad * 4 + r] = mP[r];
      lbuf[mb + quad * 4 + r] = lS[r];
    }
  }
}

__global__ __launch_bounds__(256) void attn_gcombine(
    const float* __restrict__ Obuf, const float* __restrict__ mbuf,
    const float* __restrict__ lbuf, u16* __restrict__ out)
{
  const int bh = blockIdx.x;  // 0..31
  const int b  = bh >> 4, h = bh & 15;
  const int t  = threadIdx.x;
  const int q  = t >> 4;
  const int d0 = (t & 15) * 4;
  const int mb = bh * 32 * 16;

  float mv[32];
  float M = -1e30f;
#pragma unroll
  for (int p = 0; p < 32; ++p) {
    mv[p] = mbuf[mb + p * 16 + q];
    M = fmaxf(M, mv[p]);
  }
  float L = 0.f;
  float4 acc = {0.f, 0.f, 0.f, 0.f};
#pragma unroll
  for (int p = 0; p < 32; ++p) {
    const float wp = __expf(mv[p] - M);
    L += lbuf[mb + p * 16 + q] * wp;
    float4 o = *(const float4*)&Obuf[(((size_t)(bh * 32 + p)) * 16 + q) * 64 + d0];
    acc.x += wp * o.x; acc.y += wp * o.y;
    acc.z += wp * o.z; acc.w += wp * o.w;
  }
  const float inv = 1.0f / L;
  uint2 wv;
  wv.x = (u32)f2bf(acc.x * inv) | ((u32)f2bf(acc.y * inv) << 16);
  wv.y = (u32)f2bf(acc.z * inv) | ((u32)f2bf(acc.w * inv) << 16);
  *(uint2*)(out + ((size_t)b * S_LEN + q) * 1024 + h * 64 + d0) = wv;
}

// ---------------------------------------------------------------------------
// Consolidated prep: 6 weight transposes (fp32 -> bf16) + bias concat.
// ---------------------------------------------------------------------------
__global__ __launch_bounds__(256) void prep_all(
    const float* __restrict__ Wq, const float* __restrict__ Wk,
    const float* __restrict__ Wv, const float* __restrict__ Wo,
    const float* __restrict__ W1, const float* __restrict__ W2,
    const float* __restrict__ bq, const float* __restrict__ bk,
    const float* __restrict__ bv,
    u16* __restrict__ WQKVT, u16* __restrict__ WOT,
    u16* __restrict__ W1T, u16* __restrict__ W2T,
    float* __restrict__ BQKV)
{
  const int gb = blockIdx.x;
  const int t = threadIdx.x;
  if (gb >= 3072) {  // concat
    const int i = (gb - 3072) * 256 + t;
    if (i < 1024) BQKV[i] = bq[i];
    else if (i < 2048) BQKV[i] = bk[i - 1024];
    else BQKV[i] = bv[i - 2048];
    return;
  }
  const float* in; u16* outp; int R, Cc, bx, by;
  if (gb < 1024) {
    const int seg = gb >> 8, local = gb & 255;
    bx = local & 15; by = local >> 4; R = 1024; Cc = 1024;
    in   = (seg == 0) ? Wq : (seg == 1) ? Wk : (seg == 2) ? Wv : Wo;
    outp = (seg < 3) ? WQKVT + (size_t)seg * 1024 * 1024 : WOT;
  } else if (gb < 2048) {
    const int local = gb - 1024;
    bx = local & 63; by = local >> 6; R = 1024; Cc = 4096;
    in = W1; outp = W1T;
  } else {
    const int local = gb - 2048;
    bx = local & 15; by = local >> 4; R = 4096; Cc = 1024;
    in = W2; outp = W2T;
  }

  __shared__ u16 tile[64][65];
  const int tr = by * 64, tc = bx * 64;
  const int lr = t >> 2, lc0 = (t & 3) * 16;
  const float* src = in + (size_t)(tr + lr) * Cc + tc + lc0;
  float4 a0 = *(const float4*)(src);
  float4 a1 = *(const float4*)(src + 4);
  float4 a2 = *(const float4*)(src + 8);
  float4 a3 = *(const float4*)(src + 12);
  const float vals[16] = {a0.x, a0.y, a0.z, a0.w, a1.x, a1.y, a1.z, a1.w,
                          a2.x, a2.y, a2.z, a2.w, a3.x, a3.y, a3.z, a3.w};
#pragma unroll
  for (int q = 0; q < 16; ++q) tile[lr][lc0 + q] = f2bf(vals[q]);
  __syncthreads();
  u16* dst = outp + (size_t)(tc + lr) * R + tr + lc0;
  u32 w[8];
#pragma unroll
  for (int q = 0; q < 8; ++q)
    w[q] = (u32)tile[lc0 + 2 * q][lr] | ((u32)tile[lc0 + 2 * q + 1][lr] << 16);
  uint4 s0; s0.x = w[0]; s0.y = w[1]; s0.z = w[2]; s0.w = w[3];
  uint4 s1; s1.x = w[4]; s1.y = w[5]; s1.z = w[6]; s1.w = w[7];
  *(uint4*)dst = s0;
  *(uint4*)(dst + 8) = s1;
}

// ---------------------------------------------------------------------------
// workspace layout (bytes) — ~64 MB (validated rounds 3-14).
// ---------------------------------------------------------------------------
static const size_t OFF_WQKVT = 0;                                   // bf16 [3072][1024]
static const size_t OFF_WOT   = OFF_WQKVT + (size_t)3072 * 1024 * 2; // bf16 [1024][1024]
static const size_t OFF_W1T   = OFF_WOT   + (size_t)1024 * 1024 * 2; // bf16 [4096][1024]
static const size_t OFF_W2T   = OFF_W1T   + (size_t)4096 * 1024 * 2; // bf16 [1024][4096]
static const size_t OFF_BQKV  = OFF_W2T   + (size_t)1024 * 4096 * 2; // fp32 [3072]
static const size_t OFF_XN    = OFF_BQKV  + 16384;                   // bf16 [4096][1024]
static const size_t OFF_QKV   = OFF_XN    + (size_t)4096 * 1024 * 2; // bf16 [4096][3072]
static const size_t OFF_AO    = OFF_QKV   + (size_t)4096 * 3072 * 2; // bf16 [4096][1024]
static const size_t OFF_H     = OFF_QKV;  // bf16 [4096][4096], aliases QKV+AO

extern "C" void kernel_launch(void* const* d_in, const int* in_sizes, int n_in,
                              void* d_out, int out_size, void* d_ws, size_t ws_size,
                              hipStream_t stream)
{
  const float* x   = (const float*)d_in[0];
  const float* Wq  = (const float*)d_in[1];
  const float* bq  = (const float*)d_in[2];
  const float* Wk  = (const float*)d_in[3];
  const float* bk  = (const float*)d_in[4];
  const float* Wv  = (const float*)d_in[5];
  const float* bv  = (const float*)d_in[6];
  const float* Wo  = (const float*)d_in[7];
  const float* bo  = (const float*)d_in[8];
  const float* g1  = (const float*)d_in[9];
  const float* be1 = (const float*)d_in[10];
  const float* W1  = (const float*)d_in[11];
  const float* b1  = (const float*)d_in[12];
  const float* W2  = (const float*)d_in[13];
  const float* b2  = (const float*)d_in[14];
  const float* g2  = (const float*)d_in[15];
  const float* be2 = (const float*)d_in[16];
  float* outf = (float*)d_out;
  char* ws = (char*)d_ws;

  u16*   WQKVT = (u16*)(ws + OFF_WQKVT);
  u16*   WOT   = (u16*)(ws + OFF_WOT);
  u16*   W1T   = (u16*)(ws + OFF_W1T);
  u16*   W2T   = (u16*)(ws + OFF_W2T);
  float* BQKV  = (float*)(ws + OFF_BQKV);
  u16*   XN    = (u16*)(ws + OFF_XN);
  u16*   QKV   = (u16*)(ws + OFF_QKV);
  u16*   AO    = (u16*)(ws + OFF_AO);
  u16*   Hbuf  = (u16*)(ws + OFF_H);
  float* X1    = outf;  // fp32 residual stream #2 lives in d_out
  // Wo split-K4 partials (QKV region x3 + XN)
  u16* PWo0 = (u16*)(ws + OFF_QKV);
  u16* PWo1 = PWo0 + (size_t)4096 * 1024;
  u16* PWo2 = PWo1 + (size_t)4096 * 1024;
  u16* PWo3 = (u16*)(ws + OFF_XN);
  // W2 split-K3 partials
  u16* PW20 = (u16*)(ws + OFF_W1T);
  u16* PW21 = (u16*)(ws + OFF_XN);
  u16* PW22 = (u16*)(ws + 0);     // WQKVT+WOT region (8 MB, dead after Wo)
  float* GO = (float*)(ws + OFF_XN);
  float* GM = GO + (size_t)32 * 32 * 16 * 64;
  float* GL = GM + 32 * 32 * 16;

  const dim3 blk(256);
  const dim3 blk512(512);
  prep_all<<<dim3(3084), blk, 0, stream>>>(Wq, Wk, Wv, Wo, W1, W2, bq, bk, bv,
                                           WQKVT, WOT, W1T, W2T, BQKV);

  // attention sublayer
  ln_kernel<<<dim3(ROWS), blk, 0, stream>>>(x, g1, be1, XN);
  gemm256<0, 1024><<<dim3(12, 16, 1), blk512, 0, stream>>>(
      XN, WQKVT, BQKV, QKV, QKV, QKV, QKV, 3072, 1024, 1024);
  attn_band<<<dim3(32, 32), blk, 0, stream>>>(QKV, AO);
  attn_gpart<<<dim3(8, 32), blk, 0, stream>>>(QKV, GO, GM, GL);
  attn_gcombine<<<dim3(32), blk, 0, stream>>>(GO, GM, GL, AO);
  gemm256<2, 1024><<<dim3(4, 16, 4), blk512, 0, stream>>>(
      AO, WOT, nullptr, PWo0, PWo1, PWo2, PWo3, 1024, 256, 1024);
  // fused: X1 = sum(partials)+bo+x ; XN = LN2(X1)
  reduce4_ln<<<dim3(ROWS), blk, 0, stream>>>(PWo0, PWo1, PWo2, PWo3,
                                             bo, x, g2, be2, X1, XN);

  // FFN sublayer
  gemm256<1, 1024><<<dim3(16, 16, 1), blk512, 0, stream>>>(
      XN, W1T, b1, Hbuf, Hbuf, Hbuf, Hbuf, 4096, 1024, 1024);
  gemm256<2, 4096><<<dim3(4, 16, 3), blk512, 0, stream>>>(
      Hbuf, W2T, nullptr, PW20, PW21, PW22, PW22, 1024, 1536, 4096);
  reduce3<<<dim3(2048), blk, 0, stream>>>(PW20, PW21, PW22, b2, X1, outf);
}